// Round 4
// baseline (787.141 us; speedup 1.0000x reference)
//
#include <hip/hip_runtime.h>
#include <hip/hip_bf16.h>
#include <math.h>

#define N_BATCH 8
#define WDIM 64
#define TDIM 8192
#define KBINS 2048
#define NROWS (N_BATCH * TDIM)          // 65536
#define XSIZE (N_BATCH * WDIM * TDIM)   // 4194304
#define XL_OFF 0
#define XD_OFF NROWS
#define SCAL_OFF (NROWS + XSIZE)

#define MT 64                           // rows per block
#define XST 72                          // bf16 LDS x row stride
#define TAU 0.05f
#define MAXFLAG 8192
#define NBLK (NROWS / MT)               // 1024

// ws layout (bytes):
//   0       : float k2[KBINS]            (8192)
//   8192    : int   flag_cnt
//   8256    : int   flags[MAXFLAG]       (32768)
//   41024   : u64   slots[MAXFLAG]       (65536)
//   106560  : float part[4][NBLK]        (16384)
//   122944  : char  kfrag[128*4096]      (524288)
//   647296  : float kT[64][2048]         (524288, optional)
//   1171584 : u64   res[2][NROWS]        (1048576, optional -> enables split scan)
#define WS_K2_OFF   0
#define WS_CNT_OFF  8192
#define WS_FLAG_OFF 8256
#define WS_SLOT_OFF 41024
#define WS_PART_OFF 106560
#define WS_KF_OFF   122944
#define WS_KT_OFF   647296
#define WS_KT_END   (WS_KT_OFF + (size_t)WDIM * KBINS * 4)
#define WS_RES_OFF  WS_KT_END
#define WS_RES_END  (WS_RES_OFF + (size_t)2 * NROWS * 8)

typedef __attribute__((ext_vector_type(8))) short bf16x8;
typedef __attribute__((ext_vector_type(4))) float f32x4;
typedef unsigned long long u64;

static __device__ __forceinline__ short f2bf(float v) {
  __hip_bfloat16 b = __float2bfloat16(v);
  return *reinterpret_cast<short*>(&b);
}
static __device__ __forceinline__ float bf2f(short s) {
  unsigned int u = ((unsigned int)(unsigned short)s) << 16;
  return __uint_as_float(u);
}
// monotone float<->uint order-preserving map (handles negatives)
static __device__ __forceinline__ unsigned mapm(float f) {
  unsigned u = __float_as_uint(f);
  return u ^ ((u >> 31) ? 0xFFFFFFFFu : 0x80000000u);
}
static __device__ __forceinline__ float unmapm(unsigned u) {
  unsigned b = (u & 0x80000000u) ? (u ^ 0x80000000u) : ~u;
  return __uint_as_float(b);
}

#define GLOAD_LDS(gsrc, ldst)                                            \
  __builtin_amdgcn_global_load_lds(                                      \
      (const __attribute__((address_space(1))) unsigned int*)(gsrc),     \
      (__attribute__((address_space(3))) unsigned int*)(ldst), 16, 0, 0)

// s_waitcnt immediates (gfx9): vmcnt[3:0] | expcnt<<4 | lgkmcnt<<8
#define WAIT_VM4 0x0F74
#define WAIT_VM0 0x0F70
#define SBAR() asm volatile("s_barrier" ::: "memory")

// prep: 1 block per 16-code tile. np-bit-exact k2 + fragment-ordered split-bf16
// codebook + optional kT transpose + ws init.
__global__ void prep_kernel(const float* __restrict__ kg, float* __restrict__ k2,
                            char* __restrict__ kfrag, float* __restrict__ kT,
                            int* __restrict__ cnt, u64* __restrict__ slots) {
  __shared__ float skc[16 * 65];
  const int tid  = threadIdx.x;
  const int tile = blockIdx.x;           // 0..127
  const int c0   = tile * 16;
  if (tile == 0 && tid == 0) *cnt = 0;
  if (tid < 64) slots[tile * 64 + tid] = ~0ULL;
  {
    const float4* g4 = (const float4*)(kg + (size_t)c0 * WDIM);
    int code = tid >> 4, w = (tid & 15) * 4;
    *(float4*)&skc[code * 65 + w] = g4[tid];
  }
  __syncthreads();
  if (tid < 16) {   // np-bit-exact k2 (8-accumulator pairwise)
    const float* kr = &skc[tid * 65];
    float r[8];
#pragma unroll
    for (int l = 0; l < 8; ++l) r[l] = __fmul_rn(kr[l], kr[l]);
    for (int i = 8; i < WDIM; i += 8) {
#pragma unroll
      for (int l = 0; l < 8; ++l)
        r[l] = __fadd_rn(r[l], __fmul_rn(kr[i + l], kr[i + l]));
    }
    k2[c0 + tid] = __fadd_rn(__fadd_rn(__fadd_rn(r[0], r[1]), __fadd_rn(r[2], r[3])),
                             __fadd_rn(__fadd_rn(r[4], r[5]), __fadd_rn(r[6], r[7])));
  }
  if (kT) {   // transposed copy for coalesced recheck reads (bit-exact values)
    const int code = tid & 15;
#pragma unroll
    for (int j = 0; j < 4; ++j) {
      int w = (tid >> 4) + 16 * j;
      kT[(size_t)w * KBINS + c0 + code] = skc[code * 65 + w];
    }
  }
  {
    const int sub  = tid >> 6;           // 0..3
    const int lane = tid & 63;
    const int lcol = lane & 15;
    const int quad = lane >> 4;
    const float* src = &skc[lcol * 65 + (sub & 1) * 32 + quad * 8];
    const bool lo = (sub >= 2);
    short tmp[8];
#pragma unroll
    for (int i = 0; i < 8; ++i) {
      float v = src[i];
      short h = f2bf(v);
      tmp[i] = lo ? f2bf(v - bf2f(h)) : h;
    }
    char* dst = kfrag + (size_t)tile * 4096 + sub * 1024 + lane * 16;
    *(bf16x8*)dst = *(const bf16x8*)tmp;
  }
}

// ---------------- SPLIT PATH: vq_scan (2048 blocks) + vq_emit (1024) -------
// vq_scan: block = (rowblk, half). 256 thr = 4 waves x 16 rows, scanning this
// half's 64 code tiles (R2-proven loop shape, 40 VGPR). Writes one packed key
// per (half,row): mapm(bd)<<32 | code<<1 | localTAUflag. No atomics.
// LDS 18432 -> 8 blocks/CU; VGPR<=64 -> 8 waves/SIMD -> 32 waves/CU.
__launch_bounds__(256, 8)
__global__ void vq_scan(const float* __restrict__ x,
                        const float* __restrict__ k2g,
                        const char* __restrict__ kfrag,
                        u64* __restrict__ res) {
  __shared__ __align__(16) char smem[18432];
  char*  kbuf = smem;                     // 3 x 4096 shared ring (12288)
  float* k2f  = (float*)(smem + 12288);   // this half's k2 [1024] (4096)
  // prologue overlay (dead before ring/k2f writes, barrier-protected):
  short* sxh = (short*)smem;              // [64][72] bf16 hi (9216)
  short* sxl = (short*)(smem + 9216);     // [64][72] bf16 lo (9216, ends 18432)

  const int tid    = threadIdx.x;
  const int blk    = blockIdx.x;
  const int rowblk = blk >> 1;
  const int half   = blk & 1;
  const int row0   = rowblk * MT;
  const int n      = row0 >> 13;
  const int t0     = row0 & (TDIM - 1);

  // ---- stage x tile -> split bf16 ----
  const int r  = tid & 63;
  const int wh = tid >> 6;
  const float* xb = x + (size_t)n * WDIM * TDIM + t0 + r;
#pragma unroll 8
  for (int i = 0; i < 16; ++i) {
    int w = 4 * i + wh;
    float v = xb[(size_t)w * TDIM];
    short h = f2bf(v);
    sxh[r * XST + w] = h;
    sxl[r * XST + w] = f2bf(v - bf2f(h));
  }
  __syncthreads();

  // ---- A fragments (each wave: one 16-row subtile) ----
  const int wave = tid >> 6;
  const int lane = tid & 63;
  const int lcol = lane & 15;
  const int quad = lane >> 4;
  const int rA = wave * 16 + lcol;
  bf16x8 ah0 = *(const bf16x8*)&sxh[rA * XST + 0  + quad * 8];
  bf16x8 ah1 = *(const bf16x8*)&sxh[rA * XST + 32 + quad * 8];
  bf16x8 al0 = *(const bf16x8*)&sxl[rA * XST + 0  + quad * 8];
  bf16x8 al1 = *(const bf16x8*)&sxl[rA * XST + 32 + quad * 8];
  __syncthreads();   // sxh/sxl consumed by all waves; overlays may be written

  float bd[4], b2[4];
  int   bi[4];
#pragma unroll
  for (int i = 0; i < 4; ++i) { bd[i] = 3.0e38f; b2[i] = 3.0e38f; bi[i] = 0; }

  const char* kfg = kfrag;
  const int Tb = half * 64;               // first global tile of this half

#define VQS_ISSUE(CG, B)                                                     \
  {                                                                          \
    const char* s = kfg + (size_t)(CG) * 4096 + (lane << 4);                 \
    char* d = kbuf + (B) * 4096;                                             \
    GLOAD_LDS(s, d);                                                         \
    GLOAD_LDS(s + 1024, d + 1024);                                           \
    GLOAD_LDS(s + 2048, d + 2048);                                           \
    GLOAD_LDS(s + 3072, d + 3072);                                           \
  }

  // stage this half's k2 into LDS + prime 2 ring slots
  {
    const float4* k24 = (const float4*)(k2g + half * 1024);
    *(float4*)&k2f[tid * 4] = k24[tid];
  }
  if (wave == 0) {
    VQS_ISSUE(Tb + 0, 0)
    VQS_ISSUE(Tb + 1, 1)
  }
  asm volatile("s_waitcnt lgkmcnt(0)\n\ts_barrier" ::: "memory");

#define VQS_STEP(CR, RB, PB, WAITIMM, DOISS)                                 \
  {                                                                          \
    if (wave == 0) __builtin_amdgcn_s_waitcnt(WAITIMM);                      \
    SBAR();                                                                  \
    const char* tb = kbuf + (RB) * 4096;                                     \
    bf16x8 bh0 = *(const bf16x8*)(tb + 0    + (lane << 4));                  \
    bf16x8 bh1 = *(const bf16x8*)(tb + 1024 + (lane << 4));                  \
    bf16x8 bl0 = *(const bf16x8*)(tb + 2048 + (lane << 4));                  \
    bf16x8 bl1 = *(const bf16x8*)(tb + 3072 + (lane << 4));                  \
    float k2c = k2f[(CR) * 16 + lcol];                                       \
    if (wave == 0 && (DOISS)) { VQS_ISSUE(Tb + (CR) + 2, PB) }               \
    f32x4 p = {0.f, 0.f, 0.f, 0.f};                                          \
    p = __builtin_amdgcn_mfma_f32_16x16x32_bf16(ah0, bh0, p, 0, 0, 0);       \
    p = __builtin_amdgcn_mfma_f32_16x16x32_bf16(ah1, bh1, p, 0, 0, 0);       \
    p = __builtin_amdgcn_mfma_f32_16x16x32_bf16(ah0, bl0, p, 0, 0, 0);       \
    p = __builtin_amdgcn_mfma_f32_16x16x32_bf16(ah1, bl1, p, 0, 0, 0);       \
    p = __builtin_amdgcn_mfma_f32_16x16x32_bf16(al0, bh0, p, 0, 0, 0);       \
    p = __builtin_amdgcn_mfma_f32_16x16x32_bf16(al1, bh1, p, 0, 0, 0);       \
    const int code = (Tb + (CR)) * 16 + lcol;                                \
    _Pragma("unroll")                                                        \
    for (int i = 0; i < 4; ++i) {                                            \
      float d0 = fmaf(-2.f, p[i], k2c);                                      \
      float nb2 = __builtin_amdgcn_fmed3f(bd[i], d0, b2[i]);                 \
      bool lt0 = d0 < bd[i];                                                 \
      bd[i] = lt0 ? d0 : bd[i];                                              \
      bi[i] = lt0 ? code : bi[i];                                            \
      b2[i] = nb2;                                                           \
    }                                                                        \
  }

  for (int c = 0; c < 60; c += 3) {
    VQS_STEP(c,     0, 2, WAIT_VM4, 1)
    VQS_STEP(c + 1, 1, 0, WAIT_VM4, 1)
    VQS_STEP(c + 2, 2, 1, WAIT_VM4, 1)
  }
  VQS_STEP(60, 0, 2, WAIT_VM4, 1)
  VQS_STEP(61, 1, 0, WAIT_VM4, 1)
  VQS_STEP(62, 2, 1, WAIT_VM4, 0)
  VQS_STEP(63, 0, 2, WAIT_VM0, 0)
#undef VQS_STEP
#undef VQS_ISSUE

  // ---- reduce across 16 col-classes ----
#pragma unroll
  for (int m = 1; m < 16; m <<= 1) {
#pragma unroll
    for (int i = 0; i < 4; ++i) {
      float od  = __shfl_xor(bd[i], m, 64);
      float od2 = __shfl_xor(b2[i], m, 64);
      int   oi  = __shfl_xor(bi[i], m, 64);
      float nb2 = fminf(fminf(b2[i], od2), fmaxf(bd[i], od));
      bool take = (od < bd[i]) || (od == bd[i] && oi < bi[i]);
      bd[i] = take ? od : bd[i];
      bi[i] = take ? oi : bi[i];
      b2[i] = nb2;
    }
  }

  // ---- write packed per-row keys (no atomics) ----
  if (lcol == 0) {
#pragma unroll
    for (int i = 0; i < 4; ++i) {
      int rloc = wave * 16 + quad * 4 + i;
      int rowg = row0 + rloc;
      unsigned fl = (b2[i] - bd[i] < TAU) ? 1u : 0u;
      u64 key = ((u64)mapm(bd[i]) << 32) | ((unsigned)bi[i] << 1) | fl;
      res[(size_t)half * NROWS + rowg] = key;
    }
  }
}

// vq_emit: merge halves, write xl/xd/flags + scalar partials. Memory-bound.
__launch_bounds__(256, 4)
__global__ void vq_emit(const float* __restrict__ x,
                        const float* __restrict__ kg,
                        const u64* __restrict__ res,
                        float* __restrict__ out,
                        float* __restrict__ part,
                        int* __restrict__ flag_cnt,
                        int* __restrict__ flags) {
  __shared__ __align__(16) float kd[64 * 68];   // 17408
  __shared__ int   sIdx[64];
  __shared__ float sPair[16];
  __shared__ int   sFlagCnt, sFlagBase;
  __shared__ int   sFlagList[64];

  const int tid  = threadIdx.x;
  const int blk  = blockIdx.x;
  const int row0 = blk * MT;
  const int n    = row0 >> 13;
  const int t0   = row0 & (TDIM - 1);
  const int r    = tid & 63;
  const int wh   = tid >> 6;
  const int wave = tid >> 6;
  const int lane = tid & 63;

  if (tid == 0) sFlagCnt = 0;
  __syncthreads();

  float fit_p = 0.f;
  if (tid < 64) {
    int rowg = row0 + tid;
    u64 k0 = res[rowg];
    u64 k1 = res[(size_t)NROWS + rowg];
    u64 kw = (k0 < k1) ? k0 : k1;
    u64 kl = (k0 < k1) ? k1 : k0;
    float bdw = unmapm((unsigned)(kw >> 32));
    float bdl = unmapm((unsigned)(kl >> 32));
    int code = (int)(((unsigned)kw & 0xFFFFFFFFu) >> 1) & (KBINS - 1);
    bool flag = ((unsigned)kw & 1u) || (bdl - bdw < TAU);
    out[XL_OFF + rowg] = (float)code;
    sIdx[tid] = code;
    fit_p = bdw;
    if (flag) {
      int slot = atomicAdd(&sFlagCnt, 1);
      sFlagList[slot] = rowg;
    }
  }
  __syncthreads();

  int nloc = sFlagCnt;
  if (tid == 0 && nloc > 0) sFlagBase = atomicAdd(flag_cnt, nloc);
  __syncthreads();
  if (tid < nloc) {
    int gs = sFlagBase + tid;
    if (gs < MAXFLAG) flags[gs] = sFlagList[tid];
  }

  // gather chosen code rows (fp32)
  {
    int rr = tid >> 2, q4 = tid & 3;
    const float4* kr4 = (const float4*)(kg + (size_t)sIdx[rr] * WDIM) + q4 * 4;
    float4* dst = (float4*)&kd[rr * 68 + q4 * 16];
#pragma unroll
    for (int j = 0; j < 4; ++j) dst[j] = kr4[j];
  }
  __syncthreads();

  // x_d transposed write + commit + x-scalars
  float commit_p = 0.f, x2p = 0.f, sxp = 0.f;
  const float* xb = x + (size_t)n * WDIM * TDIM + t0 + r;
  float* xdb = out + XD_OFF + (size_t)n * WDIM * TDIM + t0 + r;
#pragma unroll 8
  for (int i = 0; i < 16; ++i) {
    int w = 4 * i + wh;
    float xvv = xb[(size_t)w * TDIM];
    float kvv = kd[r * 68 + w];
    float df = kvv - xvv;
    x2p = fmaf(xvv, xvv, x2p);
    sxp += xvv;
    commit_p = fmaf(df, df, commit_p);
    xdb[(size_t)w * TDIM] = kvv;
  }

  float v0 = sxp, v1 = x2p, v2 = commit_p, v3 = fit_p;
#pragma unroll
  for (int off = 32; off > 0; off >>= 1) {
    v0 += __shfl_down(v0, off, 64);
    v1 += __shfl_down(v1, off, 64);
    v2 += __shfl_down(v2, off, 64);
    v3 += __shfl_down(v3, off, 64);
  }
  if (lane == 0) {
    sPair[wave * 4 + 0] = v0;
    sPair[wave * 4 + 1] = v1;
    sPair[wave * 4 + 2] = v2;
    sPair[wave * 4 + 3] = v3;
  }
  __syncthreads();
  if (tid == 0) {
    float s0 = 0.f, s1 = 0.f, s2 = 0.f, s3 = 0.f;
#pragma unroll
    for (int w4 = 0; w4 < 4; ++w4) {
      s0 += sPair[w4 * 4 + 0];
      s1 += sPair[w4 * 4 + 1];
      s2 += sPair[w4 * 4 + 2];
      s3 += sPair[w4 * 4 + 3];
    }
    part[0 * NBLK + blk] = s0;
    part[1 * NBLK + blk] = s1;
    part[2 * NBLK + blk] = s2;
    part[3 * NBLK + blk] = s3 + s1;   // fit row = bd + x2
  }
}

// ---------------- FALLBACK PATH (ws too small for res): R2 mono kernel -----
__launch_bounds__(256, 4)
__global__ void vq_mono(const float* __restrict__ x,
                        const float* __restrict__ kg,
                        const float* __restrict__ k2g,
                        const char* __restrict__ kfrag,
                        float* __restrict__ out,
                        float* __restrict__ part,
                        int* __restrict__ flag_cnt,
                        int* __restrict__ flags) {
  __shared__ __align__(16) char smem[20480];
  char*  kbuf = smem;
  float* k2f  = (float*)(smem + 12288);
  short* sxh = (short*)smem;
  short* sxl = (short*)(smem + 9216);
  float* kd  = (float*)smem;
  int*   sIdx      = (int*)  (smem + 18432);
  float* sPair     = (float*)(smem + 18688);
  int*   sFlagCnt  = (int*)  (smem + 18752);
  int*   sFlagBase = (int*)  (smem + 18756);
  int*   sFlagList = (int*)  (smem + 18760);

  const int tid  = threadIdx.x;
  const int blk  = blockIdx.x;
  const int row0 = blk * MT;
  const int n    = row0 >> 13;
  const int t0   = row0 & (TDIM - 1);

  const int r  = tid & 63;
  const int wh = tid >> 6;
  float x2p = 0.f, sxp = 0.f;
  const float* xb = x + (size_t)n * WDIM * TDIM + t0 + r;
#pragma unroll 8
  for (int i = 0; i < 16; ++i) {
    int w = 4 * i + wh;
    float v = xb[(size_t)w * TDIM];
    x2p = fmaf(v, v, x2p);
    sxp += v;
    short h = f2bf(v);
    sxh[r * XST + w] = h;
    sxl[r * XST + w] = f2bf(v - bf2f(h));
  }
  __syncthreads();

  const int wave = tid >> 6;
  const int lane = tid & 63;
  const int lcol = lane & 15;
  const int quad = lane >> 4;
  const int rA = wave * 16 + lcol;
  bf16x8 ah0 = *(const bf16x8*)&sxh[rA * XST + 0  + quad * 8];
  bf16x8 ah1 = *(const bf16x8*)&sxh[rA * XST + 32 + quad * 8];
  bf16x8 al0 = *(const bf16x8*)&sxl[rA * XST + 0  + quad * 8];
  bf16x8 al1 = *(const bf16x8*)&sxl[rA * XST + 32 + quad * 8];
  __syncthreads();

  float bd[4], b2[4];
  int   bi[4];
#pragma unroll
  for (int i = 0; i < 4; ++i) { bd[i] = 3.0e38f; b2[i] = 3.0e38f; bi[i] = 0; }

  const char* kfg = kfrag;

#define VQM_ISSUE(C, B)                                                      \
  if ((C) < 128) {                                                           \
    const char* s = kfg + (size_t)(C) * 4096 + (lane << 4);                  \
    char* d = kbuf + (B) * 4096;                                             \
    GLOAD_LDS(s, d);                                                         \
    GLOAD_LDS(s + 1024, d + 1024);                                           \
    GLOAD_LDS(s + 2048, d + 2048);                                           \
    GLOAD_LDS(s + 3072, d + 3072);                                           \
  }

  {
    const float4* k24 = (const float4*)k2g;
    *(float4*)&k2f[tid * 8]     = k24[tid * 2];
    *(float4*)&k2f[tid * 8 + 4] = k24[tid * 2 + 1];
  }
  if (wave == 0) {
    VQM_ISSUE(0, 0)
    VQM_ISSUE(1, 1)
  }
  asm volatile("s_waitcnt lgkmcnt(0)\n\ts_barrier" ::: "memory");

#define VQM_STEP(C, RB, PB, WAITIMM)                                         \
  {                                                                          \
    if (wave == 0) __builtin_amdgcn_s_waitcnt(WAITIMM);                      \
    SBAR();                                                                  \
    const char* tb = kbuf + (RB) * 4096;                                     \
    bf16x8 bh0 = *(const bf16x8*)(tb + 0    + (lane << 4));                  \
    bf16x8 bh1 = *(const bf16x8*)(tb + 1024 + (lane << 4));                  \
    bf16x8 bl0 = *(const bf16x8*)(tb + 2048 + (lane << 4));                  \
    bf16x8 bl1 = *(const bf16x8*)(tb + 3072 + (lane << 4));                  \
    float k2c = k2f[(C) * 16 + lcol];                                        \
    if (wave == 0) { VQM_ISSUE((C) + 2, PB) }                                \
    f32x4 p = {0.f, 0.f, 0.f, 0.f};                                          \
    p = __builtin_amdgcn_mfma_f32_16x16x32_bf16(ah0, bh0, p, 0, 0, 0);       \
    p = __builtin_amdgcn_mfma_f32_16x16x32_bf16(ah1, bh1, p, 0, 0, 0);       \
    p = __builtin_amdgcn_mfma_f32_16x16x32_bf16(ah0, bl0, p, 0, 0, 0);       \
    p = __builtin_amdgcn_mfma_f32_16x16x32_bf16(ah1, bl1, p, 0, 0, 0);       \
    p = __builtin_amdgcn_mfma_f32_16x16x32_bf16(al0, bh0, p, 0, 0, 0);       \
    p = __builtin_amdgcn_mfma_f32_16x16x32_bf16(al1, bh1, p, 0, 0, 0);       \
    const int code = (C) * 16 + lcol;                                        \
    _Pragma("unroll")                                                        \
    for (int i = 0; i < 4; ++i) {                                            \
      float d0 = fmaf(-2.f, p[i], k2c);                                      \
      float nb2 = __builtin_amdgcn_fmed3f(bd[i], d0, b2[i]);                 \
      bool lt0 = d0 < bd[i];                                                 \
      bd[i] = lt0 ? d0 : bd[i];                                              \
      bi[i] = lt0 ? code : bi[i];                                            \
      b2[i] = nb2;                                                           \
    }                                                                        \
  }

  for (int c = 0; c < 126; c += 3) {
    VQM_STEP(c,     0, 2, WAIT_VM4)
    VQM_STEP(c + 1, 1, 0, WAIT_VM4)
    VQM_STEP(c + 2, 2, 1, WAIT_VM4)
  }
  VQM_STEP(126, 0, 2, WAIT_VM4)
  VQM_STEP(127, 1, 0, WAIT_VM0)
#undef VQM_STEP
#undef VQM_ISSUE

#pragma unroll
  for (int m = 1; m < 16; m <<= 1) {
#pragma unroll
    for (int i = 0; i < 4; ++i) {
      float od  = __shfl_xor(bd[i], m, 64);
      float od2 = __shfl_xor(b2[i], m, 64);
      int   oi  = __shfl_xor(bi[i], m, 64);
      float nb2 = fminf(fminf(b2[i], od2), fmaxf(bd[i], od));
      bool take = (od < bd[i]) || (od == bd[i] && oi < bi[i]);
      bd[i] = take ? od : bd[i];
      bi[i] = take ? oi : bi[i];
      b2[i] = nb2;
    }
  }

  __syncthreads();
  if (tid == 0) *sFlagCnt = 0;
  __syncthreads();

  float fit_p = 0.f;
  if (lcol == 0) {
#pragma unroll
    for (int i = 0; i < 4; ++i) {
      int rloc = wave * 16 + quad * 4 + i;
      int rowg = row0 + rloc;
      out[XL_OFF + rowg] = (float)bi[i];
      sIdx[rloc] = bi[i];
      fit_p += bd[i];
      if (b2[i] - bd[i] < TAU) {
        int slot = atomicAdd(sFlagCnt, 1);
        sFlagList[slot] = rowg;
      }
    }
  }
  __syncthreads();

  int nloc = *sFlagCnt;
  if (tid == 0 && nloc > 0) *sFlagBase = atomicAdd(flag_cnt, nloc);
  __syncthreads();
  if (tid < nloc) {
    int gs = *sFlagBase + tid;
    if (gs < MAXFLAG) flags[gs] = sFlagList[tid];
  }

  {
    int rr = tid >> 2, q4 = tid & 3;
    const float4* kr4 = (const float4*)(kg + (size_t)sIdx[rr] * WDIM) + q4 * 4;
    float4* dst = (float4*)&kd[rr * 68 + q4 * 16];
#pragma unroll
    for (int j = 0; j < 4; ++j) dst[j] = kr4[j];
  }
  __syncthreads();

  float commit_p = 0.f;
  float* xdb = out + XD_OFF + (size_t)n * WDIM * TDIM + t0 + r;
#pragma unroll 8
  for (int i = 0; i < 16; ++i) {
    int w = 4 * i + wh;
    float xvv = xb[(size_t)w * TDIM];
    float kvv = kd[r * 68 + w];
    float df = kvv - xvv;
    commit_p = fmaf(df, df, commit_p);
    xdb[(size_t)w * TDIM] = kvv;
  }

  float v0 = sxp, v1 = x2p, v2 = commit_p, v3 = fit_p;
#pragma unroll
  for (int off = 32; off > 0; off >>= 1) {
    v0 += __shfl_down(v0, off, 64);
    v1 += __shfl_down(v1, off, 64);
    v2 += __shfl_down(v2, off, 64);
    v3 += __shfl_down(v3, off, 64);
  }
  if (lane == 0) {
    sPair[wave * 4 + 0] = v0;
    sPair[wave * 4 + 1] = v1;
    sPair[wave * 4 + 2] = v2;
    sPair[wave * 4 + 3] = v3;
  }
  __syncthreads();
  if (tid == 0) {
    float x2sum = sPair[1] + sPair[5] + sPair[9] + sPair[13];
    part[0 * NBLK + blk] = sPair[0] + sPair[4] + sPair[8] + sPair[12];
    part[1 * NBLK + blk] = x2sum;
    part[2 * NBLK + blk] = sPair[2] + sPair[6] + sPair[10] + sPair[14];
    part[3 * NBLK + blk] = (sPair[3] + sPair[7] + sPair[11] + sPair[15]) + x2sum;
  }
}

// recheck pass 1: ONE BLOCK PER FLAGGED ROW (grid-stride). 256 thr, 8 codes
// per thread via coalesced kT columns. x row loaded once per row (was 8x).
// Identical fmaf chain per code -> bit-identical distances vs previous rounds.
__launch_bounds__(256, 4)
__global__ void recheck_scan(const float* __restrict__ x,
                             const float* __restrict__ kg,
                             const float* __restrict__ kT,
                             const float* __restrict__ k2g,
                             const int* __restrict__ flag_cnt,
                             const int* __restrict__ flags,
                             u64* __restrict__ slots) {
  __shared__ float sx[WDIM];
  __shared__ float sx2s;
  __shared__ u64 swm[4];
  const int tid  = threadIdx.x;
  const int lane = tid & 63;
  const int wv   = tid >> 6;
  int nf = *flag_cnt;
  if (nf > MAXFLAG) nf = MAXFLAG;

  for (int fi = blockIdx.x; fi < nf; fi += 1024) {
    const int row = flags[fi];
    const int n = row >> 13;
    const int t = row & (TDIM - 1);
    if (tid < WDIM) sx[tid] = x[(size_t)n * WDIM * TDIM + (size_t)tid * TDIM + t];
    __syncthreads();
    if (tid == 0) {   // np-pairwise x2
      float r8[8];
#pragma unroll
      for (int l = 0; l < 8; ++l) r8[l] = __fmul_rn(sx[l], sx[l]);
      for (int i = 8; i < WDIM; i += 8) {
#pragma unroll
        for (int l = 0; l < 8; ++l)
          r8[l] = __fadd_rn(r8[l], __fmul_rn(sx[i + l], sx[i + l]));
      }
      sx2s = __fadd_rn(__fadd_rn(__fadd_rn(r8[0], r8[1]), __fadd_rn(r8[2], r8[3])),
                       __fadd_rn(__fadd_rn(r8[4], r8[5]), __fadd_rn(r8[6], r8[7])));
    }
    __syncthreads();

    u64 best = ~0ULL;
#pragma unroll
    for (int s = 0; s < 8; ++s) {
      const int j = s * 256 + tid;
      float c = 0.f;
      if (kT) {
#pragma unroll
        for (int w = 0; w < WDIM; ++w)
          c = __fmaf_rn(sx[w], kT[(size_t)w * KBINS + j], c);
      } else {
        const float* kr = kg + (size_t)j * WDIM;
#pragma unroll
        for (int w = 0; w < WDIM; ++w)
          c = __fmaf_rn(sx[w], kr[w], c);
      }
      float d = __fadd_rn(__fsub_rn(sx2s, __fmul_rn(2.0f, c)), k2g[j]);
      u64 key = ((u64)__float_as_uint(d) << 32) | (unsigned)j;
      best = (key < best) ? key : best;
    }
#pragma unroll
    for (int off = 32; off > 0; off >>= 1) {
      u64 o = __shfl_down((unsigned long long)best, off, 64);
      if (o < best) best = o;
    }
    if (lane == 0) swm[wv] = best;
    __syncthreads();
    if (tid == 0) {
      u64 b = swm[0];
#pragma unroll
      for (int k = 1; k < 4; ++k) b = (swm[k] < b) ? swm[k] : b;
      atomicMin(&slots[fi], b);
    }
    __syncthreads();
  }
}

// recheck pass 2: persistent write-back.
__global__ void recheck_write(const float* __restrict__ kg,
                              const int* __restrict__ flag_cnt,
                              const int* __restrict__ flags,
                              const u64* __restrict__ slots,
                              float* __restrict__ out) {
  int nf = *flag_cnt;
  if (nf > MAXFLAG) nf = MAXFLAG;
  const int w = threadIdx.x;
  for (int fi = blockIdx.x; fi < nf; fi += 256) {
    const int row = flags[fi];
    const int n = row >> 13;
    const int t = row & (TDIM - 1);
    const int j = (int)(slots[fi] & 0xFFFFFFFFULL);
    if (w == 0) out[XL_OFF + row] = (float)j;
    out[XD_OFF + (size_t)n * WDIM * TDIM + (size_t)w * TDIM + t] = kg[(size_t)j * WDIM + w];
  }
}

// finalize: sum per-block partials (fp64) + emit the 3 scalars.
__global__ void finalize_kernel(const float* __restrict__ part, float* __restrict__ out) {
  __shared__ double sred[4][64];
  const int tid = threadIdx.x;     // 256
  const int lane = tid & 63;
  const int wv = tid >> 6;
  double a[4] = {0.0, 0.0, 0.0, 0.0};
  for (int i = tid; i < NBLK; i += 256) {
#pragma unroll
    for (int q = 0; q < 4; ++q) a[q] += (double)part[q * NBLK + i];
  }
#pragma unroll
  for (int off = 32; off > 0; off >>= 1) {
#pragma unroll
    for (int q = 0; q < 4; ++q)
      a[q] += __shfl_down(a[q], off, 64);
  }
  if (lane == 0) {
#pragma unroll
    for (int q = 0; q < 4; ++q) sred[q][wv] = a[q];
  }
  __syncthreads();
  if (tid == 0) {
    double s0 = 0, s1 = 0, s2 = 0, s3 = 0;
#pragma unroll
    for (int wv2 = 0; wv2 < 4; ++wv2) {
      s0 += sred[0][wv2]; s1 += sred[1][wv2];
      s2 += sred[2][wv2]; s3 += sred[3][wv2];
    }
    double size = (double)XSIZE;
    double commit = s2 / size;
    double fit = s3 / (double)NROWS;
    double mean = s0 / size;
    double var = s1 / size - mean * mean;
    if (var < 0.0) var = 0.0;
    out[SCAL_OFF + 0] = (float)commit;
    out[SCAL_OFF + 1] = (float)fit;
    out[SCAL_OFF + 2] = (float)sqrt(var);
  }
}

extern "C" void kernel_launch(void* const* d_in, const int* in_sizes, int n_in,
                              void* d_out, int out_size, void* d_ws, size_t ws_size,
                              hipStream_t stream) {
  const float* x = (const float*)d_in[0];
  const float* kg = (const float*)d_in[1];
  float* out = (float*)d_out;
  float* k2   = (float*)((char*)d_ws + WS_K2_OFF);
  int* cnt    = (int*)((char*)d_ws + WS_CNT_OFF);
  int* flags  = (int*)((char*)d_ws + WS_FLAG_OFF);
  u64* slots  = (u64*)((char*)d_ws + WS_SLOT_OFF);
  float* part = (float*)((char*)d_ws + WS_PART_OFF);
  char* kfrag = (char*)d_ws + WS_KF_OFF;
  float* kT   = (ws_size >= WS_KT_END) ? (float*)((char*)d_ws + WS_KT_OFF) : nullptr;
  u64* res    = (ws_size >= WS_RES_END) ? (u64*)((char*)d_ws + WS_RES_OFF) : nullptr;

  hipLaunchKernelGGL(prep_kernel, dim3(KBINS / 16), dim3(256), 0, stream,
                     kg, k2, kfrag, kT, cnt, slots);
  if (res) {
    hipLaunchKernelGGL(vq_scan, dim3(2 * NBLK), dim3(256), 0, stream,
                       x, k2, kfrag, res);
    hipLaunchKernelGGL(vq_emit, dim3(NBLK), dim3(256), 0, stream,
                       x, kg, res, out, part, cnt, flags);
  } else {
    hipLaunchKernelGGL(vq_mono, dim3(NBLK), dim3(256), 0, stream,
                       x, kg, k2, kfrag, out, part, cnt, flags);
  }
  hipLaunchKernelGGL(recheck_scan, dim3(1024), dim3(256), 0, stream,
                     x, kg, kT, k2, cnt, flags, slots);
  hipLaunchKernelGGL(recheck_write, dim3(256), dim3(WDIM), 0, stream,
                     kg, cnt, flags, slots, out);
  hipLaunchKernelGGL(finalize_kernel, dim3(1), dim3(256), 0, stream, part, out);
}

// Round 5
// 227.815 us; speedup vs baseline: 3.4552x; 3.4552x over previous
//
#include <hip/hip_runtime.h>
#include <hip/hip_bf16.h>
#include <math.h>

#define N_BATCH 8
#define WDIM 64
#define TDIM 8192
#define KBINS 2048
#define NROWS (N_BATCH * TDIM)          // 65536
#define XSIZE (N_BATCH * WDIM * TDIM)   // 4194304
#define XL_OFF 0
#define XD_OFF NROWS
#define SCAL_OFF (NROWS + XSIZE)

#define MT 64                           // rows per block
#define XST 72                          // bf16 LDS x row stride
#define TAU 0.05f
#define MAXFLAG 8192
#define NBLK (NROWS / MT)               // 1024

// ws layout (bytes):
//   0       : float k2[KBINS]            (8192)
//   8192    : int   flag_cnt
//   8256    : int   flags[MAXFLAG]       (32768)
//   41024   : u64   slots[MAXFLAG]       (65536)
//   106560  : float part[4][NBLK]        (16384)
//   122944  : char  kfrag[128*4096]      (524288)
//   647296  : float kT[64][2048]         (524288, optional)
//   1171584 : u64   res[2][NROWS]        (1048576, optional -> enables split scan)
#define WS_K2_OFF   0
#define WS_CNT_OFF  8192
#define WS_FLAG_OFF 8256
#define WS_SLOT_OFF 41024
#define WS_PART_OFF 106560
#define WS_KF_OFF   122944
#define WS_KT_OFF   647296
#define WS_KT_END   (WS_KT_OFF + (size_t)WDIM * KBINS * 4)
#define WS_RES_OFF  WS_KT_END
#define WS_RES_END  (WS_RES_OFF + (size_t)2 * NROWS * 8)

typedef __attribute__((ext_vector_type(8))) short bf16x8;
typedef __attribute__((ext_vector_type(4))) float f32x4;
typedef unsigned long long u64;

static __device__ __forceinline__ short f2bf(float v) {
  __hip_bfloat16 b = __float2bfloat16(v);
  return *reinterpret_cast<short*>(&b);
}
static __device__ __forceinline__ float bf2f(short s) {
  unsigned int u = ((unsigned int)(unsigned short)s) << 16;
  return __uint_as_float(u);
}
// monotone float<->uint order-preserving map (handles negatives)
static __device__ __forceinline__ unsigned mapm(float f) {
  unsigned u = __float_as_uint(f);
  return u ^ ((u >> 31) ? 0xFFFFFFFFu : 0x80000000u);
}
static __device__ __forceinline__ float unmapm(unsigned u) {
  unsigned b = (u & 0x80000000u) ? (u ^ 0x80000000u) : ~u;
  return __uint_as_float(b);
}

#define GLOAD_LDS(gsrc, ldst)                                            \
  __builtin_amdgcn_global_load_lds(                                      \
      (const __attribute__((address_space(1))) unsigned int*)(gsrc),     \
      (__attribute__((address_space(3))) unsigned int*)(ldst), 16, 0, 0)

// s_waitcnt immediates (gfx9): vmcnt[3:0] | expcnt<<4 | lgkmcnt<<8
#define WAIT_VM4 0x0F74
#define WAIT_VM0 0x0F70
#define SBAR() asm volatile("s_barrier" ::: "memory")

// prep: 1 block per 16-code tile. np-bit-exact k2 + fragment-ordered split-bf16
// codebook + optional kT transpose + ws init.
__global__ void prep_kernel(const float* __restrict__ kg, float* __restrict__ k2,
                            char* __restrict__ kfrag, float* __restrict__ kT,
                            int* __restrict__ cnt, u64* __restrict__ slots) {
  __shared__ float skc[16 * 65];
  const int tid  = threadIdx.x;
  const int tile = blockIdx.x;           // 0..127
  const int c0   = tile * 16;
  if (tile == 0 && tid == 0) *cnt = 0;
  if (tid < 64) slots[tile * 64 + tid] = ~0ULL;
  {
    const float4* g4 = (const float4*)(kg + (size_t)c0 * WDIM);
    int code = tid >> 4, w = (tid & 15) * 4;
    *(float4*)&skc[code * 65 + w] = g4[tid];
  }
  __syncthreads();
  if (tid < 16) {   // np-bit-exact k2 (8-accumulator pairwise)
    const float* kr = &skc[tid * 65];
    float r[8];
#pragma unroll
    for (int l = 0; l < 8; ++l) r[l] = __fmul_rn(kr[l], kr[l]);
    for (int i = 8; i < WDIM; i += 8) {
#pragma unroll
      for (int l = 0; l < 8; ++l)
        r[l] = __fadd_rn(r[l], __fmul_rn(kr[i + l], kr[i + l]));
    }
    k2[c0 + tid] = __fadd_rn(__fadd_rn(__fadd_rn(r[0], r[1]), __fadd_rn(r[2], r[3])),
                             __fadd_rn(__fadd_rn(r[4], r[5]), __fadd_rn(r[6], r[7])));
  }
  if (kT) {   // transposed copy for coalesced recheck reads (bit-exact values)
    const int code = tid & 15;
#pragma unroll
    for (int j = 0; j < 4; ++j) {
      int w = (tid >> 4) + 16 * j;
      kT[(size_t)w * KBINS + c0 + code] = skc[code * 65 + w];
    }
  }
  {
    const int sub  = tid >> 6;           // 0..3
    const int lane = tid & 63;
    const int lcol = lane & 15;
    const int quad = lane >> 4;
    const float* src = &skc[lcol * 65 + (sub & 1) * 32 + quad * 8];
    const bool lo = (sub >= 2);
    short tmp[8];
#pragma unroll
    for (int i = 0; i < 8; ++i) {
      float v = src[i];
      short h = f2bf(v);
      tmp[i] = lo ? f2bf(v - bf2f(h)) : h;
    }
    char* dst = kfrag + (size_t)tile * 4096 + sub * 1024 + lane * 16;
    *(bf16x8*)dst = *(const bf16x8*)tmp;
  }
}

// ---------------- SPLIT PATH: vq_scan (2048 blocks) + vq_emit (1024) -------
// vq_scan: block = (rowblk, half). 256 thr = 4 waves x 16 rows, scanning this
// half's 64 code tiles (R2-proven loop shape, ~40 VGPR). Writes one packed key
// per (half,row): mapm(bd)<<32 | code<<1 | localTAUflag. No atomics.
// LDS 18432 -> 8 blocks/CU; VGPR<=64 -> 8 waves/SIMD -> 32 waves/CU.
__launch_bounds__(256, 8)
__global__ void vq_scan(const float* __restrict__ x,
                        const float* __restrict__ k2g,
                        const char* __restrict__ kfrag,
                        u64* __restrict__ res) {
  __shared__ __align__(16) char smem[18432];
  char*  kbuf = smem;                     // 3 x 4096 shared ring (12288)
  float* k2f  = (float*)(smem + 12288);   // this half's k2 [1024] (4096)
  // prologue overlay (dead before ring/k2f writes, barrier-protected):
  short* sxh = (short*)smem;              // [64][72] bf16 hi (9216)
  short* sxl = (short*)(smem + 9216);     // [64][72] bf16 lo (9216, ends 18432)

  const int tid    = threadIdx.x;
  const int blk    = blockIdx.x;
  const int rowblk = blk >> 1;
  const int half   = blk & 1;
  const int row0   = rowblk * MT;
  const int n      = row0 >> 13;
  const int t0     = row0 & (TDIM - 1);

  // ---- stage x tile -> split bf16 ----
  const int r  = tid & 63;
  const int wh = tid >> 6;
  const float* xb = x + (size_t)n * WDIM * TDIM + t0 + r;
#pragma unroll 8
  for (int i = 0; i < 16; ++i) {
    int w = 4 * i + wh;
    float v = xb[(size_t)w * TDIM];
    short h = f2bf(v);
    sxh[r * XST + w] = h;
    sxl[r * XST + w] = f2bf(v - bf2f(h));
  }
  __syncthreads();

  // ---- A fragments (each wave: one 16-row subtile) ----
  const int wave = tid >> 6;
  const int lane = tid & 63;
  const int lcol = lane & 15;
  const int quad = lane >> 4;
  const int rA = wave * 16 + lcol;
  bf16x8 ah0 = *(const bf16x8*)&sxh[rA * XST + 0  + quad * 8];
  bf16x8 ah1 = *(const bf16x8*)&sxh[rA * XST + 32 + quad * 8];
  bf16x8 al0 = *(const bf16x8*)&sxl[rA * XST + 0  + quad * 8];
  bf16x8 al1 = *(const bf16x8*)&sxl[rA * XST + 32 + quad * 8];
  __syncthreads();   // sxh/sxl consumed by all waves; overlays may be written

  float bd[4], b2[4];
  int   bi[4];
#pragma unroll
  for (int i = 0; i < 4; ++i) { bd[i] = 3.0e38f; b2[i] = 3.0e38f; bi[i] = 0; }

  const char* kfg = kfrag;
  const int Tb = half * 64;               // first global tile of this half

#define VQS_ISSUE(CG, B)                                                     \
  {                                                                          \
    const char* s = kfg + (size_t)(CG) * 4096 + (lane << 4);                 \
    char* d = kbuf + (B) * 4096;                                             \
    GLOAD_LDS(s, d);                                                         \
    GLOAD_LDS(s + 1024, d + 1024);                                           \
    GLOAD_LDS(s + 2048, d + 2048);                                           \
    GLOAD_LDS(s + 3072, d + 3072);                                           \
  }

  // stage this half's k2 into LDS + prime 2 ring slots
  {
    const float4* k24 = (const float4*)(k2g + half * 1024);
    *(float4*)&k2f[tid * 4] = k24[tid];
  }
  if (wave == 0) {
    VQS_ISSUE(Tb + 0, 0)
    VQS_ISSUE(Tb + 1, 1)
  }
  asm volatile("s_waitcnt lgkmcnt(0)\n\ts_barrier" ::: "memory");

#define VQS_STEP(CR, RB, PB, WAITIMM, DOISS)                                 \
  {                                                                          \
    if (wave == 0) __builtin_amdgcn_s_waitcnt(WAITIMM);                      \
    SBAR();                                                                  \
    const char* tb = kbuf + (RB) * 4096;                                     \
    bf16x8 bh0 = *(const bf16x8*)(tb + 0    + (lane << 4));                  \
    bf16x8 bh1 = *(const bf16x8*)(tb + 1024 + (lane << 4));                  \
    bf16x8 bl0 = *(const bf16x8*)(tb + 2048 + (lane << 4));                  \
    bf16x8 bl1 = *(const bf16x8*)(tb + 3072 + (lane << 4));                  \
    float k2c = k2f[(CR) * 16 + lcol];                                       \
    if (wave == 0 && (DOISS)) { VQS_ISSUE(Tb + (CR) + 2, PB) }               \
    f32x4 p = {0.f, 0.f, 0.f, 0.f};                                          \
    p = __builtin_amdgcn_mfma_f32_16x16x32_bf16(ah0, bh0, p, 0, 0, 0);       \
    p = __builtin_amdgcn_mfma_f32_16x16x32_bf16(ah1, bh1, p, 0, 0, 0);       \
    p = __builtin_amdgcn_mfma_f32_16x16x32_bf16(ah0, bl0, p, 0, 0, 0);       \
    p = __builtin_amdgcn_mfma_f32_16x16x32_bf16(ah1, bl1, p, 0, 0, 0);       \
    p = __builtin_amdgcn_mfma_f32_16x16x32_bf16(al0, bh0, p, 0, 0, 0);       \
    p = __builtin_amdgcn_mfma_f32_16x16x32_bf16(al1, bh1, p, 0, 0, 0);       \
    const int code = (Tb + (CR)) * 16 + lcol;                                \
    _Pragma("unroll")                                                        \
    for (int i = 0; i < 4; ++i) {                                            \
      float d0 = fmaf(-2.f, p[i], k2c);                                      \
      float nb2 = __builtin_amdgcn_fmed3f(bd[i], d0, b2[i]);                 \
      bool lt0 = d0 < bd[i];                                                 \
      bd[i] = lt0 ? d0 : bd[i];                                              \
      bi[i] = lt0 ? code : bi[i];                                            \
      b2[i] = nb2;                                                           \
    }                                                                        \
  }

  for (int c = 0; c < 60; c += 3) {
    VQS_STEP(c,     0, 2, WAIT_VM4, 1)
    VQS_STEP(c + 1, 1, 0, WAIT_VM4, 1)
    VQS_STEP(c + 2, 2, 1, WAIT_VM4, 1)
  }
  VQS_STEP(60, 0, 2, WAIT_VM4, 1)
  VQS_STEP(61, 1, 0, WAIT_VM4, 1)
  VQS_STEP(62, 2, 1, WAIT_VM4, 0)
  VQS_STEP(63, 0, 2, WAIT_VM0, 0)
#undef VQS_STEP
#undef VQS_ISSUE

  // ---- reduce across 16 col-classes ----
#pragma unroll
  for (int m = 1; m < 16; m <<= 1) {
#pragma unroll
    for (int i = 0; i < 4; ++i) {
      float od  = __shfl_xor(bd[i], m, 64);
      float od2 = __shfl_xor(b2[i], m, 64);
      int   oi  = __shfl_xor(bi[i], m, 64);
      float nb2 = fminf(fminf(b2[i], od2), fmaxf(bd[i], od));
      bool take = (od < bd[i]) || (od == bd[i] && oi < bi[i]);
      bd[i] = take ? od : bd[i];
      bi[i] = take ? oi : bi[i];
      b2[i] = nb2;
    }
  }

  // ---- write packed per-row keys (no atomics) ----
  if (lcol == 0) {
#pragma unroll
    for (int i = 0; i < 4; ++i) {
      int rloc = wave * 16 + quad * 4 + i;
      int rowg = row0 + rloc;
      unsigned fl = (b2[i] - bd[i] < TAU) ? 1u : 0u;
      u64 key = ((u64)mapm(bd[i]) << 32) | ((unsigned)bi[i] << 1) | fl;
      res[(size_t)half * NROWS + rowg] = key;
    }
  }
}

// vq_emit: merge halves, write xl/xd/flags + scalar partials. Memory-bound.
__launch_bounds__(256, 4)
__global__ void vq_emit(const float* __restrict__ x,
                        const float* __restrict__ kg,
                        const u64* __restrict__ res,
                        float* __restrict__ out,
                        float* __restrict__ part,
                        int* __restrict__ flag_cnt,
                        int* __restrict__ flags) {
  __shared__ __align__(16) float kd[64 * 68];   // 17408
  __shared__ int   sIdx[64];
  __shared__ float sPair[16];
  __shared__ int   sFlagCnt, sFlagBase;
  __shared__ int   sFlagList[64];

  const int tid  = threadIdx.x;
  const int blk  = blockIdx.x;
  const int row0 = blk * MT;
  const int n    = row0 >> 13;
  const int t0   = row0 & (TDIM - 1);
  const int r    = tid & 63;
  const int wh   = tid >> 6;
  const int wave = tid >> 6;
  const int lane = tid & 63;

  if (tid == 0) sFlagCnt = 0;
  __syncthreads();

  float fit_p = 0.f;
  if (tid < 64) {
    int rowg = row0 + tid;
    u64 k0 = res[rowg];
    u64 k1 = res[(size_t)NROWS + rowg];
    u64 kw = (k0 < k1) ? k0 : k1;
    u64 kl = (k0 < k1) ? k1 : k0;
    float bdw = unmapm((unsigned)(kw >> 32));
    float bdl = unmapm((unsigned)(kl >> 32));
    int code = (int)(((unsigned)kw & 0xFFFFFFFFu) >> 1) & (KBINS - 1);
    bool flag = ((unsigned)kw & 1u) || (bdl - bdw < TAU);
    out[XL_OFF + rowg] = (float)code;
    sIdx[tid] = code;
    fit_p = bdw;
    if (flag) {
      int slot = atomicAdd(&sFlagCnt, 1);
      sFlagList[slot] = rowg;
    }
  }
  __syncthreads();

  int nloc = sFlagCnt;
  if (tid == 0 && nloc > 0) sFlagBase = atomicAdd(flag_cnt, nloc);
  __syncthreads();
  if (tid < nloc) {
    int gs = sFlagBase + tid;
    if (gs < MAXFLAG) flags[gs] = sFlagList[tid];
  }

  // gather chosen code rows (fp32)
  {
    int rr = tid >> 2, q4 = tid & 3;
    const float4* kr4 = (const float4*)(kg + (size_t)sIdx[rr] * WDIM) + q4 * 4;
    float4* dst = (float4*)&kd[rr * 68 + q4 * 16];
#pragma unroll
    for (int j = 0; j < 4; ++j) dst[j] = kr4[j];
  }
  __syncthreads();

  // x_d transposed write + commit + x-scalars
  float commit_p = 0.f, x2p = 0.f, sxp = 0.f;
  const float* xb = x + (size_t)n * WDIM * TDIM + t0 + r;
  float* xdb = out + XD_OFF + (size_t)n * WDIM * TDIM + t0 + r;
#pragma unroll 8
  for (int i = 0; i < 16; ++i) {
    int w = 4 * i + wh;
    float xvv = xb[(size_t)w * TDIM];
    float kvv = kd[r * 68 + w];
    float df = kvv - xvv;
    x2p = fmaf(xvv, xvv, x2p);
    sxp += xvv;
    commit_p = fmaf(df, df, commit_p);
    xdb[(size_t)w * TDIM] = kvv;
  }

  float v0 = sxp, v1 = x2p, v2 = commit_p, v3 = fit_p;
#pragma unroll
  for (int off = 32; off > 0; off >>= 1) {
    v0 += __shfl_down(v0, off, 64);
    v1 += __shfl_down(v1, off, 64);
    v2 += __shfl_down(v2, off, 64);
    v3 += __shfl_down(v3, off, 64);
  }
  if (lane == 0) {
    sPair[wave * 4 + 0] = v0;
    sPair[wave * 4 + 1] = v1;
    sPair[wave * 4 + 2] = v2;
    sPair[wave * 4 + 3] = v3;
  }
  __syncthreads();
  if (tid == 0) {
    float s0 = 0.f, s1 = 0.f, s2 = 0.f, s3 = 0.f;
#pragma unroll
    for (int w4 = 0; w4 < 4; ++w4) {
      s0 += sPair[w4 * 4 + 0];
      s1 += sPair[w4 * 4 + 1];
      s2 += sPair[w4 * 4 + 2];
      s3 += sPair[w4 * 4 + 3];
    }
    part[0 * NBLK + blk] = s0;
    part[1 * NBLK + blk] = s1;
    part[2 * NBLK + blk] = s2;
    part[3 * NBLK + blk] = s3 + s1;   // fit row = bd + x2
  }
}

// ---------------- FALLBACK PATH (ws too small for res): R2 mono kernel -----
__launch_bounds__(256, 4)
__global__ void vq_mono(const float* __restrict__ x,
                        const float* __restrict__ kg,
                        const float* __restrict__ k2g,
                        const char* __restrict__ kfrag,
                        float* __restrict__ out,
                        float* __restrict__ part,
                        int* __restrict__ flag_cnt,
                        int* __restrict__ flags) {
  __shared__ __align__(16) char smem[20480];
  char*  kbuf = smem;
  float* k2f  = (float*)(smem + 12288);
  short* sxh = (short*)smem;
  short* sxl = (short*)(smem + 9216);
  float* kd  = (float*)smem;
  int*   sIdx      = (int*)  (smem + 18432);
  float* sPair     = (float*)(smem + 18688);
  int*   sFlagCnt  = (int*)  (smem + 18752);
  int*   sFlagBase = (int*)  (smem + 18756);
  int*   sFlagList = (int*)  (smem + 18760);

  const int tid  = threadIdx.x;
  const int blk  = blockIdx.x;
  const int row0 = blk * MT;
  const int n    = row0 >> 13;
  const int t0   = row0 & (TDIM - 1);

  const int r  = tid & 63;
  const int wh = tid >> 6;
  float x2p = 0.f, sxp = 0.f;
  const float* xb = x + (size_t)n * WDIM * TDIM + t0 + r;
#pragma unroll 8
  for (int i = 0; i < 16; ++i) {
    int w = 4 * i + wh;
    float v = xb[(size_t)w * TDIM];
    x2p = fmaf(v, v, x2p);
    sxp += v;
    short h = f2bf(v);
    sxh[r * XST + w] = h;
    sxl[r * XST + w] = f2bf(v - bf2f(h));
  }
  __syncthreads();

  const int wave = tid >> 6;
  const int lane = tid & 63;
  const int lcol = lane & 15;
  const int quad = lane >> 4;
  const int rA = wave * 16 + lcol;
  bf16x8 ah0 = *(const bf16x8*)&sxh[rA * XST + 0  + quad * 8];
  bf16x8 ah1 = *(const bf16x8*)&sxh[rA * XST + 32 + quad * 8];
  bf16x8 al0 = *(const bf16x8*)&sxl[rA * XST + 0  + quad * 8];
  bf16x8 al1 = *(const bf16x8*)&sxl[rA * XST + 32 + quad * 8];
  __syncthreads();

  float bd[4], b2[4];
  int   bi[4];
#pragma unroll
  for (int i = 0; i < 4; ++i) { bd[i] = 3.0e38f; b2[i] = 3.0e38f; bi[i] = 0; }

  const char* kfg = kfrag;

#define VQM_ISSUE(C, B)                                                      \
  if ((C) < 128) {                                                           \
    const char* s = kfg + (size_t)(C) * 4096 + (lane << 4);                  \
    char* d = kbuf + (B) * 4096;                                             \
    GLOAD_LDS(s, d);                                                         \
    GLOAD_LDS(s + 1024, d + 1024);                                           \
    GLOAD_LDS(s + 2048, d + 2048);                                           \
    GLOAD_LDS(s + 3072, d + 3072);                                           \
  }

  {
    const float4* k24 = (const float4*)k2g;
    *(float4*)&k2f[tid * 8]     = k24[tid * 2];
    *(float4*)&k2f[tid * 8 + 4] = k24[tid * 2 + 1];
  }
  if (wave == 0) {
    VQM_ISSUE(0, 0)
    VQM_ISSUE(1, 1)
  }
  asm volatile("s_waitcnt lgkmcnt(0)\n\ts_barrier" ::: "memory");

#define VQM_STEP(C, RB, PB, WAITIMM)                                         \
  {                                                                          \
    if (wave == 0) __builtin_amdgcn_s_waitcnt(WAITIMM);                      \
    SBAR();                                                                  \
    const char* tb = kbuf + (RB) * 4096;                                     \
    bf16x8 bh0 = *(const bf16x8*)(tb + 0    + (lane << 4));                  \
    bf16x8 bh1 = *(const bf16x8*)(tb + 1024 + (lane << 4));                  \
    bf16x8 bl0 = *(const bf16x8*)(tb + 2048 + (lane << 4));                  \
    bf16x8 bl1 = *(const bf16x8*)(tb + 3072 + (lane << 4));                  \
    float k2c = k2f[(C) * 16 + lcol];                                        \
    if (wave == 0) { VQM_ISSUE((C) + 2, PB) }                                \
    f32x4 p = {0.f, 0.f, 0.f, 0.f};                                          \
    p = __builtin_amdgcn_mfma_f32_16x16x32_bf16(ah0, bh0, p, 0, 0, 0);       \
    p = __builtin_amdgcn_mfma_f32_16x16x32_bf16(ah1, bh1, p, 0, 0, 0);       \
    p = __builtin_amdgcn_mfma_f32_16x16x32_bf16(ah0, bl0, p, 0, 0, 0);       \
    p = __builtin_amdgcn_mfma_f32_16x16x32_bf16(ah1, bl1, p, 0, 0, 0);       \
    p = __builtin_amdgcn_mfma_f32_16x16x32_bf16(al0, bh0, p, 0, 0, 0);       \
    p = __builtin_amdgcn_mfma_f32_16x16x32_bf16(al1, bh1, p, 0, 0, 0);       \
    const int code = (C) * 16 + lcol;                                        \
    _Pragma("unroll")                                                        \
    for (int i = 0; i < 4; ++i) {                                            \
      float d0 = fmaf(-2.f, p[i], k2c);                                      \
      float nb2 = __builtin_amdgcn_fmed3f(bd[i], d0, b2[i]);                 \
      bool lt0 = d0 < bd[i];                                                 \
      bd[i] = lt0 ? d0 : bd[i];                                              \
      bi[i] = lt0 ? code : bi[i];                                            \
      b2[i] = nb2;                                                           \
    }                                                                        \
  }

  for (int c = 0; c < 126; c += 3) {
    VQM_STEP(c,     0, 2, WAIT_VM4)
    VQM_STEP(c + 1, 1, 0, WAIT_VM4)
    VQM_STEP(c + 2, 2, 1, WAIT_VM4)
  }
  VQM_STEP(126, 0, 2, WAIT_VM4)
  VQM_STEP(127, 1, 0, WAIT_VM0)
#undef VQM_STEP
#undef VQM_ISSUE

#pragma unroll
  for (int m = 1; m < 16; m <<= 1) {
#pragma unroll
    for (int i = 0; i < 4; ++i) {
      float od  = __shfl_xor(bd[i], m, 64);
      float od2 = __shfl_xor(b2[i], m, 64);
      int   oi  = __shfl_xor(bi[i], m, 64);
      float nb2 = fminf(fminf(b2[i], od2), fmaxf(bd[i], od));
      bool take = (od < bd[i]) || (od == bd[i] && oi < bi[i]);
      bd[i] = take ? od : bd[i];
      bi[i] = take ? oi : bi[i];
      b2[i] = nb2;
    }
  }

  __syncthreads();
  if (tid == 0) *sFlagCnt = 0;
  __syncthreads();

  float fit_p = 0.f;
  if (lcol == 0) {
#pragma unroll
    for (int i = 0; i < 4; ++i) {
      int rloc = wave * 16 + quad * 4 + i;
      int rowg = row0 + rloc;
      out[XL_OFF + rowg] = (float)bi[i];
      sIdx[rloc] = bi[i];
      fit_p += bd[i];
      if (b2[i] - bd[i] < TAU) {
        int slot = atomicAdd(sFlagCnt, 1);
        sFlagList[slot] = rowg;
      }
    }
  }
  __syncthreads();

  int nloc = *sFlagCnt;
  if (tid == 0 && nloc > 0) *sFlagBase = atomicAdd(flag_cnt, nloc);
  __syncthreads();
  if (tid < nloc) {
    int gs = *sFlagBase + tid;
    if (gs < MAXFLAG) flags[gs] = sFlagList[tid];
  }

  {
    int rr = tid >> 2, q4 = tid & 3;
    const float4* kr4 = (const float4*)(kg + (size_t)sIdx[rr] * WDIM) + q4 * 4;
    float4* dst = (float4*)&kd[rr * 68 + q4 * 16];
#pragma unroll
    for (int j = 0; j < 4; ++j) dst[j] = kr4[j];
  }
  __syncthreads();

  float commit_p = 0.f;
  float* xdb = out + XD_OFF + (size_t)n * WDIM * TDIM + t0 + r;
#pragma unroll 8
  for (int i = 0; i < 16; ++i) {
    int w = 4 * i + wh;
    float xvv = xb[(size_t)w * TDIM];
    float kvv = kd[r * 68 + w];
    float df = kvv - xvv;
    commit_p = fmaf(df, df, commit_p);
    xdb[(size_t)w * TDIM] = kvv;
  }

  float v0 = sxp, v1 = x2p, v2 = commit_p, v3 = fit_p;
#pragma unroll
  for (int off = 32; off > 0; off >>= 1) {
    v0 += __shfl_down(v0, off, 64);
    v1 += __shfl_down(v1, off, 64);
    v2 += __shfl_down(v2, off, 64);
    v3 += __shfl_down(v3, off, 64);
  }
  if (lane == 0) {
    sPair[wave * 4 + 0] = v0;
    sPair[wave * 4 + 1] = v1;
    sPair[wave * 4 + 2] = v2;
    sPair[wave * 4 + 3] = v3;
  }
  __syncthreads();
  if (tid == 0) {
    float x2sum = sPair[1] + sPair[5] + sPair[9] + sPair[13];
    part[0 * NBLK + blk] = sPair[0] + sPair[4] + sPair[8] + sPair[12];
    part[1 * NBLK + blk] = x2sum;
    part[2 * NBLK + blk] = sPair[2] + sPair[6] + sPair[10] + sPair[14];
    part[3 * NBLK + blk] = (sPair[3] + sPair[7] + sPair[11] + sPair[15]) + x2sum;
  }
}

// recheck pass 1 (R2/R3-proven form): persistent grid; item = (flagged row,
// 256-code segment). kT coalesced; identical fmaf chain -> bit-identical
// distances. Lean registers (no outer unroll) -> no scratch.
__launch_bounds__(256, 4)
__global__ void recheck_scan(const float* __restrict__ x,
                             const float* __restrict__ kg,
                             const float* __restrict__ kT,
                             const float* __restrict__ k2g,
                             const int* __restrict__ flag_cnt,
                             const int* __restrict__ flags,
                             u64* __restrict__ slots) {
  __shared__ float sx[WDIM];
  __shared__ float sx2s;
  const int tid = threadIdx.x;
  int nf = *flag_cnt;
  if (nf > MAXFLAG) nf = MAXFLAG;
  const int total = nf * 8;

  for (int g = blockIdx.x; g < total; g += 2048) {
    const int fi  = g >> 3;
    const int seg = g & 7;
    const int row = flags[fi];
    const int n = row >> 13;
    const int t = row & (TDIM - 1);
    if (tid < WDIM) sx[tid] = x[(size_t)n * WDIM * TDIM + (size_t)tid * TDIM + t];
    __syncthreads();
    if (tid == 0) {   // np-pairwise x2
      float r8[8];
#pragma unroll
      for (int l = 0; l < 8; ++l) r8[l] = __fmul_rn(sx[l], sx[l]);
      for (int i = 8; i < WDIM; i += 8) {
#pragma unroll
        for (int l = 0; l < 8; ++l)
          r8[l] = __fadd_rn(r8[l], __fmul_rn(sx[i + l], sx[i + l]));
      }
      sx2s = __fadd_rn(__fadd_rn(__fadd_rn(r8[0], r8[1]), __fadd_rn(r8[2], r8[3])),
                       __fadd_rn(__fadd_rn(r8[4], r8[5]), __fadd_rn(r8[6], r8[7])));
    }
    __syncthreads();

    const int j = seg * 256 + tid;
    float c = 0.f;
    if (kT) {
#pragma unroll
      for (int w = 0; w < WDIM; ++w)
        c = __fmaf_rn(sx[w], kT[(size_t)w * KBINS + j], c);
    } else {
      const float* kr = kg + (size_t)j * WDIM;
#pragma unroll
      for (int w = 0; w < WDIM; ++w)
        c = __fmaf_rn(sx[w], kr[w], c);
    }
    float d = __fadd_rn(__fsub_rn(sx2s, __fmul_rn(2.0f, c)), k2g[j]);

    u64 key = ((u64)__float_as_uint(d) << 32) | (unsigned)j;
#pragma unroll
    for (int off = 32; off > 0; off >>= 1) {
      u64 o = __shfl_down((unsigned long long)key, off, 64);
      if (o < key) key = o;
    }
    if ((tid & 63) == 0) atomicMin(&slots[fi], key);
    __syncthreads();
  }
}

// recheck pass 2: persistent write-back.
__global__ void recheck_write(const float* __restrict__ kg,
                              const int* __restrict__ flag_cnt,
                              const int* __restrict__ flags,
                              const u64* __restrict__ slots,
                              float* __restrict__ out) {
  int nf = *flag_cnt;
  if (nf > MAXFLAG) nf = MAXFLAG;
  const int w = threadIdx.x;
  for (int fi = blockIdx.x; fi < nf; fi += 256) {
    const int row = flags[fi];
    const int n = row >> 13;
    const int t = row & (TDIM - 1);
    const int j = (int)(slots[fi] & 0xFFFFFFFFULL);
    if (w == 0) out[XL_OFF + row] = (float)j;
    out[XD_OFF + (size_t)n * WDIM * TDIM + (size_t)w * TDIM + t] = kg[(size_t)j * WDIM + w];
  }
}

// finalize: sum per-block partials (fp64) + emit the 3 scalars.
__global__ void finalize_kernel(const float* __restrict__ part, float* __restrict__ out) {
  __shared__ double sred[4][64];
  const int tid = threadIdx.x;     // 256
  const int lane = tid & 63;
  const int wv = tid >> 6;
  double a[4] = {0.0, 0.0, 0.0, 0.0};
  for (int i = tid; i < NBLK; i += 256) {
#pragma unroll
    for (int q = 0; q < 4; ++q) a[q] += (double)part[q * NBLK + i];
  }
#pragma unroll
  for (int off = 32; off > 0; off >>= 1) {
#pragma unroll
    for (int q = 0; q < 4; ++q)
      a[q] += __shfl_down(a[q], off, 64);
  }
  if (lane == 0) {
#pragma unroll
    for (int q = 0; q < 4; ++q) sred[q][wv] = a[q];
  }
  __syncthreads();
  if (tid == 0) {
    double s0 = 0, s1 = 0, s2 = 0, s3 = 0;
#pragma unroll
    for (int wv2 = 0; wv2 < 4; ++wv2) {
      s0 += sred[0][wv2]; s1 += sred[1][wv2];
      s2 += sred[2][wv2]; s3 += sred[3][wv2];
    }
    double size = (double)XSIZE;
    double commit = s2 / size;
    double fit = s3 / (double)NROWS;
    double mean = s0 / size;
    double var = s1 / size - mean * mean;
    if (var < 0.0) var = 0.0;
    out[SCAL_OFF + 0] = (float)commit;
    out[SCAL_OFF + 1] = (float)fit;
    out[SCAL_OFF + 2] = (float)sqrt(var);
  }
}

extern "C" void kernel_launch(void* const* d_in, const int* in_sizes, int n_in,
                              void* d_out, int out_size, void* d_ws, size_t ws_size,
                              hipStream_t stream) {
  const float* x = (const float*)d_in[0];
  const float* kg = (const float*)d_in[1];
  float* out = (float*)d_out;
  float* k2   = (float*)((char*)d_ws + WS_K2_OFF);
  int* cnt    = (int*)((char*)d_ws + WS_CNT_OFF);
  int* flags  = (int*)((char*)d_ws + WS_FLAG_OFF);
  u64* slots  = (u64*)((char*)d_ws + WS_SLOT_OFF);
  float* part = (float*)((char*)d_ws + WS_PART_OFF);
  char* kfrag = (char*)d_ws + WS_KF_OFF;
  float* kT   = (ws_size >= WS_KT_END) ? (float*)((char*)d_ws + WS_KT_OFF) : nullptr;
  u64* res    = (ws_size >= WS_RES_END) ? (u64*)((char*)d_ws + WS_RES_OFF) : nullptr;

  hipLaunchKernelGGL(prep_kernel, dim3(KBINS / 16), dim3(256), 0, stream,
                     kg, k2, kfrag, kT, cnt, slots);
  if (res) {
    hipLaunchKernelGGL(vq_scan, dim3(2 * NBLK), dim3(256), 0, stream,
                       x, k2, kfrag, res);
    hipLaunchKernelGGL(vq_emit, dim3(NBLK), dim3(256), 0, stream,
                       x, kg, res, out, part, cnt, flags);
  } else {
    hipLaunchKernelGGL(vq_mono, dim3(NBLK), dim3(256), 0, stream,
                       x, kg, k2, kfrag, out, part, cnt, flags);
  }
  hipLaunchKernelGGL(recheck_scan, dim3(2048), dim3(256), 0, stream,
                     x, kg, kT, k2, cnt, flags, slots);
  hipLaunchKernelGGL(recheck_write, dim3(256), dim3(WDIM), 0, stream,
                     kg, cnt, flags, slots, out);
  hipLaunchKernelGGL(finalize_kernel, dim3(1), dim3(256), 0, stream, part, out);
}

// Round 6
// 177.466 us; speedup vs baseline: 4.4355x; 1.2837x over previous
//
#include <hip/hip_runtime.h>
#include <hip/hip_bf16.h>
#include <math.h>

#define N_BATCH 8
#define WDIM 64
#define TDIM 8192
#define KBINS 2048
#define NROWS (N_BATCH * TDIM)          // 65536
#define XSIZE (N_BATCH * WDIM * TDIM)   // 4194304
#define XL_OFF 0
#define XD_OFF NROWS
#define SCAL_OFF (NROWS + XSIZE)

#define MT 64                           // rows per block
#define XST 72                          // bf16 LDS x row stride
#define TAU 0.05f
#define MAXFLAG 8192
#define NBLK (NROWS / MT)               // 1024

// ws layout (bytes):
//   0       : float k2[KBINS]            (8192)
//   8192    : int   flag_cnt
//   8256    : int   flags[MAXFLAG]       (32768)
//   41024   : u64   slots[MAXFLAG]       (65536)
//   106560  : float part[4][NBLK]        (16384)
//   122944  : char  kfrag[128*4096]      (524288)
//   647296  : float kT[64][2048]         (524288, optional)
//   1171584 : u64   res[2][NROWS]        (1048576, optional -> enables split scan)
#define WS_K2_OFF   0
#define WS_CNT_OFF  8192
#define WS_FLAG_OFF 8256
#define WS_SLOT_OFF 41024
#define WS_PART_OFF 106560
#define WS_KF_OFF   122944
#define WS_KT_OFF   647296
#define WS_KT_END   (WS_KT_OFF + (size_t)WDIM * KBINS * 4)
#define WS_RES_OFF  WS_KT_END
#define WS_RES_END  (WS_RES_OFF + (size_t)2 * NROWS * 8)

typedef __attribute__((ext_vector_type(8))) short bf16x8;
typedef __attribute__((ext_vector_type(4))) float f32x4;
typedef unsigned long long u64;

static __device__ __forceinline__ short f2bf(float v) {
  __hip_bfloat16 b = __float2bfloat16(v);
  return *reinterpret_cast<short*>(&b);
}
static __device__ __forceinline__ float bf2f(short s) {
  unsigned int u = ((unsigned int)(unsigned short)s) << 16;
  return __uint_as_float(u);
}
// monotone float<->uint order-preserving map (handles negatives)
static __device__ __forceinline__ unsigned mapm(float f) {
  unsigned u = __float_as_uint(f);
  return u ^ ((u >> 31) ? 0xFFFFFFFFu : 0x80000000u);
}
static __device__ __forceinline__ float unmapm(unsigned u) {
  unsigned b = (u & 0x80000000u) ? (u ^ 0x80000000u) : ~u;
  return __uint_as_float(b);
}

#define GLOAD_LDS(gsrc, ldst)                                            \
  __builtin_amdgcn_global_load_lds(                                      \
      (const __attribute__((address_space(1))) unsigned int*)(gsrc),     \
      (__attribute__((address_space(3))) unsigned int*)(ldst), 16, 0, 0)

// s_waitcnt immediates (gfx9): vmcnt[3:0] | expcnt<<4 | lgkmcnt<<8
#define WAIT_VM4 0x0F74
#define WAIT_VM0 0x0F70
#define SBAR() asm volatile("s_barrier" ::: "memory")

// prep: 1 block per 16-code tile. np-bit-exact k2 + fragment-ordered split-bf16
// codebook + optional kT transpose + ws init.
__global__ void prep_kernel(const float* __restrict__ kg, float* __restrict__ k2,
                            char* __restrict__ kfrag, float* __restrict__ kT,
                            int* __restrict__ cnt, u64* __restrict__ slots) {
  __shared__ float skc[16 * 65];
  const int tid  = threadIdx.x;
  const int tile = blockIdx.x;           // 0..127
  const int c0   = tile * 16;
  if (tile == 0 && tid == 0) *cnt = 0;
  if (tid < 64) slots[tile * 64 + tid] = ~0ULL;
  {
    const float4* g4 = (const float4*)(kg + (size_t)c0 * WDIM);
    int code = tid >> 4, w = (tid & 15) * 4;
    *(float4*)&skc[code * 65 + w] = g4[tid];
  }
  __syncthreads();
  if (tid < 16) {   // np-bit-exact k2 (8-accumulator pairwise)
    const float* kr = &skc[tid * 65];
    float r[8];
#pragma unroll
    for (int l = 0; l < 8; ++l) r[l] = __fmul_rn(kr[l], kr[l]);
    for (int i = 8; i < WDIM; i += 8) {
#pragma unroll
      for (int l = 0; l < 8; ++l)
        r[l] = __fadd_rn(r[l], __fmul_rn(kr[i + l], kr[i + l]));
    }
    k2[c0 + tid] = __fadd_rn(__fadd_rn(__fadd_rn(r[0], r[1]), __fadd_rn(r[2], r[3])),
                             __fadd_rn(__fadd_rn(r[4], r[5]), __fadd_rn(r[6], r[7])));
  }
  if (kT) {   // transposed copy for coalesced recheck reads (bit-exact values)
    const int code = tid & 15;
#pragma unroll
    for (int j = 0; j < 4; ++j) {
      int w = (tid >> 4) + 16 * j;
      kT[(size_t)w * KBINS + c0 + code] = skc[code * 65 + w];
    }
  }
  {
    const int sub  = tid >> 6;           // 0..3
    const int lane = tid & 63;
    const int lcol = lane & 15;
    const int quad = lane >> 4;
    const float* src = &skc[lcol * 65 + (sub & 1) * 32 + quad * 8];
    const bool lo = (sub >= 2);
    short tmp[8];
#pragma unroll
    for (int i = 0; i < 8; ++i) {
      float v = src[i];
      short h = f2bf(v);
      tmp[i] = lo ? f2bf(v - bf2f(h)) : h;
    }
    char* dst = kfrag + (size_t)tile * 4096 + sub * 1024 + lane * 16;
    *(bf16x8*)dst = *(const bf16x8*)tmp;
  }
}

// ---------------- SPLIT PATH: vq_scan (2048 blocks) + vq_emit (1024) -------
// vq_scan: block b -> (rowblk = b & 1023, half = b >> 10). Same-row pairs are
// 1024 dispatch slots apart -> same XCD (1024 % 8 == 0) -> the duplicated x
// tile read hits that XCD's L2 instead of HBM.
// 256 thr = 4 waves x 16 rows, scanning this half's 64 code tiles (R2-proven
// loop, ~40 VGPR natural). Writes one packed key per (half,row):
// mapm(bd)<<32 | code<<1 | localTAUflag. No atomics.
// OCCUPANCY: LDS 18432 -> 8 blocks/CU is the binding limit = 32 waves/CU.
// launch_bounds(256,4) (128-VGPR ceiling) lets the allocator take its natural
// ~40 VGPR -- NO forced 64-cap, NO spills (R5's spill: 30 MB scratch, 2x dur).
__launch_bounds__(256, 4)
__global__ void vq_scan(const float* __restrict__ x,
                        const float* __restrict__ k2g,
                        const char* __restrict__ kfrag,
                        u64* __restrict__ res) {
  __shared__ __align__(16) char smem[18432];
  char*  kbuf = smem;                     // 3 x 4096 shared ring (12288)
  float* k2f  = (float*)(smem + 12288);   // this half's k2 [1024] (4096)
  // prologue overlay (dead before ring/k2f writes, barrier-protected):
  short* sxh = (short*)smem;              // [64][72] bf16 hi (9216)
  short* sxl = (short*)(smem + 9216);     // [64][72] bf16 lo (9216, ends 18432)

  const int tid    = threadIdx.x;
  const int blk    = blockIdx.x;
  const int rowblk = blk & (NBLK - 1);
  const int half   = blk >> 10;
  const int row0   = rowblk * MT;
  const int n      = row0 >> 13;
  const int t0     = row0 & (TDIM - 1);

  // ---- stage x tile -> split bf16 ----
  const int r  = tid & 63;
  const int wh = tid >> 6;
  const float* xb = x + (size_t)n * WDIM * TDIM + t0 + r;
#pragma unroll 8
  for (int i = 0; i < 16; ++i) {
    int w = 4 * i + wh;
    float v = xb[(size_t)w * TDIM];
    short h = f2bf(v);
    sxh[r * XST + w] = h;
    sxl[r * XST + w] = f2bf(v - bf2f(h));
  }
  __syncthreads();

  // ---- A fragments (each wave: one 16-row subtile) ----
  const int wave = tid >> 6;
  const int lane = tid & 63;
  const int lcol = lane & 15;
  const int quad = lane >> 4;
  const int rA = wave * 16 + lcol;
  bf16x8 ah0 = *(const bf16x8*)&sxh[rA * XST + 0  + quad * 8];
  bf16x8 ah1 = *(const bf16x8*)&sxh[rA * XST + 32 + quad * 8];
  bf16x8 al0 = *(const bf16x8*)&sxl[rA * XST + 0  + quad * 8];
  bf16x8 al1 = *(const bf16x8*)&sxl[rA * XST + 32 + quad * 8];
  __syncthreads();   // sxh/sxl consumed by all waves; overlays may be written

  float bd[4], b2[4];
  int   bi[4];
#pragma unroll
  for (int i = 0; i < 4; ++i) { bd[i] = 3.0e38f; b2[i] = 3.0e38f; bi[i] = 0; }

  const char* kfg = kfrag;
  const int Tb = half * 64;               // first global tile of this half

#define VQS_ISSUE(CG, B)                                                     \
  {                                                                          \
    const char* s = kfg + (size_t)(CG) * 4096 + (lane << 4);                 \
    char* d = kbuf + (B) * 4096;                                             \
    GLOAD_LDS(s, d);                                                         \
    GLOAD_LDS(s + 1024, d + 1024);                                           \
    GLOAD_LDS(s + 2048, d + 2048);                                           \
    GLOAD_LDS(s + 3072, d + 3072);                                           \
  }

  // stage this half's k2 into LDS + prime 2 ring slots
  {
    const float4* k24 = (const float4*)(k2g + half * 1024);
    *(float4*)&k2f[tid * 4] = k24[tid];
  }
  if (wave == 0) {
    VQS_ISSUE(Tb + 0, 0)
    VQS_ISSUE(Tb + 1, 1)
  }
  asm volatile("s_waitcnt lgkmcnt(0)\n\ts_barrier" ::: "memory");

#define VQS_STEP(CR, RB, PB, WAITIMM, DOISS)                                 \
  {                                                                          \
    if (wave == 0) __builtin_amdgcn_s_waitcnt(WAITIMM);                      \
    SBAR();                                                                  \
    const char* tb = kbuf + (RB) * 4096;                                     \
    bf16x8 bh0 = *(const bf16x8*)(tb + 0    + (lane << 4));                  \
    bf16x8 bh1 = *(const bf16x8*)(tb + 1024 + (lane << 4));                  \
    bf16x8 bl0 = *(const bf16x8*)(tb + 2048 + (lane << 4));                  \
    bf16x8 bl1 = *(const bf16x8*)(tb + 3072 + (lane << 4));                  \
    float k2c = k2f[(CR) * 16 + lcol];                                       \
    if (wave == 0 && (DOISS)) { VQS_ISSUE(Tb + (CR) + 2, PB) }               \
    f32x4 p = {0.f, 0.f, 0.f, 0.f};                                          \
    p = __builtin_amdgcn_mfma_f32_16x16x32_bf16(ah0, bh0, p, 0, 0, 0);       \
    p = __builtin_amdgcn_mfma_f32_16x16x32_bf16(ah1, bh1, p, 0, 0, 0);       \
    p = __builtin_amdgcn_mfma_f32_16x16x32_bf16(ah0, bl0, p, 0, 0, 0);       \
    p = __builtin_amdgcn_mfma_f32_16x16x32_bf16(ah1, bl1, p, 0, 0, 0);       \
    p = __builtin_amdgcn_mfma_f32_16x16x32_bf16(al0, bh0, p, 0, 0, 0);       \
    p = __builtin_amdgcn_mfma_f32_16x16x32_bf16(al1, bh1, p, 0, 0, 0);       \
    const int code = (Tb + (CR)) * 16 + lcol;                                \
    _Pragma("unroll")                                                        \
    for (int i = 0; i < 4; ++i) {                                            \
      float d0 = fmaf(-2.f, p[i], k2c);                                      \
      float nb2 = __builtin_amdgcn_fmed3f(bd[i], d0, b2[i]);                 \
      bool lt0 = d0 < bd[i];                                                 \
      bd[i] = lt0 ? d0 : bd[i];                                              \
      bi[i] = lt0 ? code : bi[i];                                            \
      b2[i] = nb2;                                                           \
    }                                                                        \
  }

  for (int c = 0; c < 60; c += 3) {
    VQS_STEP(c,     0, 2, WAIT_VM4, 1)
    VQS_STEP(c + 1, 1, 0, WAIT_VM4, 1)
    VQS_STEP(c + 2, 2, 1, WAIT_VM4, 1)
  }
  VQS_STEP(60, 0, 2, WAIT_VM4, 1)
  VQS_STEP(61, 1, 0, WAIT_VM4, 1)
  VQS_STEP(62, 2, 1, WAIT_VM4, 0)
  VQS_STEP(63, 0, 2, WAIT_VM0, 0)
#undef VQS_STEP
#undef VQS_ISSUE

  // ---- reduce across 16 col-classes ----
#pragma unroll
  for (int m = 1; m < 16; m <<= 1) {
#pragma unroll
    for (int i = 0; i < 4; ++i) {
      float od  = __shfl_xor(bd[i], m, 64);
      float od2 = __shfl_xor(b2[i], m, 64);
      int   oi  = __shfl_xor(bi[i], m, 64);
      float nb2 = fminf(fminf(b2[i], od2), fmaxf(bd[i], od));
      bool take = (od < bd[i]) || (od == bd[i] && oi < bi[i]);
      bd[i] = take ? od : bd[i];
      bi[i] = take ? oi : bi[i];
      b2[i] = nb2;
    }
  }

  // ---- write packed per-row keys (no atomics) ----
  if (lcol == 0) {
#pragma unroll
    for (int i = 0; i < 4; ++i) {
      int rloc = wave * 16 + quad * 4 + i;
      int rowg = row0 + rloc;
      unsigned fl = (b2[i] - bd[i] < TAU) ? 1u : 0u;
      u64 key = ((u64)mapm(bd[i]) << 32) | ((unsigned)bi[i] << 1) | fl;
      res[(size_t)half * NROWS + rowg] = key;
    }
  }
}

// vq_emit: merge halves, write xl/xd/flags + scalar partials. Memory-bound.
__launch_bounds__(256, 4)
__global__ void vq_emit(const float* __restrict__ x,
                        const float* __restrict__ kg,
                        const u64* __restrict__ res,
                        float* __restrict__ out,
                        float* __restrict__ part,
                        int* __restrict__ flag_cnt,
                        int* __restrict__ flags) {
  __shared__ __align__(16) float kd[64 * 68];   // 17408
  __shared__ int   sIdx[64];
  __shared__ float sPair[16];
  __shared__ int   sFlagCnt, sFlagBase;
  __shared__ int   sFlagList[64];

  const int tid  = threadIdx.x;
  const int blk  = blockIdx.x;
  const int row0 = blk * MT;
  const int n    = row0 >> 13;
  const int t0   = row0 & (TDIM - 1);
  const int r    = tid & 63;
  const int wh   = tid >> 6;
  const int wave = tid >> 6;
  const int lane = tid & 63;

  if (tid == 0) sFlagCnt = 0;
  __syncthreads();

  float fit_p = 0.f;
  if (tid < 64) {
    int rowg = row0 + tid;
    u64 k0 = res[rowg];
    u64 k1 = res[(size_t)NROWS + rowg];
    u64 kw = (k0 < k1) ? k0 : k1;
    u64 kl = (k0 < k1) ? k1 : k0;
    float bdw = unmapm((unsigned)(kw >> 32));
    float bdl = unmapm((unsigned)(kl >> 32));
    int code = (int)(((unsigned)kw & 0xFFFFFFFFu) >> 1) & (KBINS - 1);
    bool flag = ((unsigned)kw & 1u) || (bdl - bdw < TAU);
    out[XL_OFF + rowg] = (float)code;
    sIdx[tid] = code;
    fit_p = bdw;
    if (flag) {
      int slot = atomicAdd(&sFlagCnt, 1);
      sFlagList[slot] = rowg;
    }
  }
  __syncthreads();

  int nloc = sFlagCnt;
  if (tid == 0 && nloc > 0) sFlagBase = atomicAdd(flag_cnt, nloc);
  __syncthreads();
  if (tid < nloc) {
    int gs = sFlagBase + tid;
    if (gs < MAXFLAG) flags[gs] = sFlagList[tid];
  }

  // gather chosen code rows (fp32)
  {
    int rr = tid >> 2, q4 = tid & 3;
    const float4* kr4 = (const float4*)(kg + (size_t)sIdx[rr] * WDIM) + q4 * 4;
    float4* dst = (float4*)&kd[rr * 68 + q4 * 16];
#pragma unroll
    for (int j = 0; j < 4; ++j) dst[j] = kr4[j];
  }
  __syncthreads();

  // x_d transposed write + commit + x-scalars
  float commit_p = 0.f, x2p = 0.f, sxp = 0.f;
  const float* xb = x + (size_t)n * WDIM * TDIM + t0 + r;
  float* xdb = out + XD_OFF + (size_t)n * WDIM * TDIM + t0 + r;
#pragma unroll 8
  for (int i = 0; i < 16; ++i) {
    int w = 4 * i + wh;
    float xvv = xb[(size_t)w * TDIM];
    float kvv = kd[r * 68 + w];
    float df = kvv - xvv;
    x2p = fmaf(xvv, xvv, x2p);
    sxp += xvv;
    commit_p = fmaf(df, df, commit_p);
    xdb[(size_t)w * TDIM] = kvv;
  }

  float v0 = sxp, v1 = x2p, v2 = commit_p, v3 = fit_p;
#pragma unroll
  for (int off = 32; off > 0; off >>= 1) {
    v0 += __shfl_down(v0, off, 64);
    v1 += __shfl_down(v1, off, 64);
    v2 += __shfl_down(v2, off, 64);
    v3 += __shfl_down(v3, off, 64);
  }
  if (lane == 0) {
    sPair[wave * 4 + 0] = v0;
    sPair[wave * 4 + 1] = v1;
    sPair[wave * 4 + 2] = v2;
    sPair[wave * 4 + 3] = v3;
  }
  __syncthreads();
  if (tid == 0) {
    float s0 = 0.f, s1 = 0.f, s2 = 0.f, s3 = 0.f;
#pragma unroll
    for (int w4 = 0; w4 < 4; ++w4) {
      s0 += sPair[w4 * 4 + 0];
      s1 += sPair[w4 * 4 + 1];
      s2 += sPair[w4 * 4 + 2];
      s3 += sPair[w4 * 4 + 3];
    }
    part[0 * NBLK + blk] = s0;
    part[1 * NBLK + blk] = s1;
    part[2 * NBLK + blk] = s2;
    part[3 * NBLK + blk] = s3 + s1;   // fit row = bd + x2
  }
}

// ---------------- FALLBACK PATH (ws too small for res): R2 mono kernel -----
__launch_bounds__(256, 4)
__global__ void vq_mono(const float* __restrict__ x,
                        const float* __restrict__ kg,
                        const float* __restrict__ k2g,
                        const char* __restrict__ kfrag,
                        float* __restrict__ out,
                        float* __restrict__ part,
                        int* __restrict__ flag_cnt,
                        int* __restrict__ flags) {
  __shared__ __align__(16) char smem[20480];
  char*  kbuf = smem;
  float* k2f  = (float*)(smem + 12288);
  short* sxh = (short*)smem;
  short* sxl = (short*)(smem + 9216);
  float* kd  = (float*)smem;
  int*   sIdx      = (int*)  (smem + 18432);
  float* sPair     = (float*)(smem + 18688);
  int*   sFlagCnt  = (int*)  (smem + 18752);
  int*   sFlagBase = (int*)  (smem + 18756);
  int*   sFlagList = (int*)  (smem + 18760);

  const int tid  = threadIdx.x;
  const int blk  = blockIdx.x;
  const int row0 = blk * MT;
  const int n    = row0 >> 13;
  const int t0   = row0 & (TDIM - 1);

  const int r  = tid & 63;
  const int wh = tid >> 6;
  float x2p = 0.f, sxp = 0.f;
  const float* xb = x + (size_t)n * WDIM * TDIM + t0 + r;
#pragma unroll 8
  for (int i = 0; i < 16; ++i) {
    int w = 4 * i + wh;
    float v = xb[(size_t)w * TDIM];
    x2p = fmaf(v, v, x2p);
    sxp += v;
    short h = f2bf(v);
    sxh[r * XST + w] = h;
    sxl[r * XST + w] = f2bf(v - bf2f(h));
  }
  __syncthreads();

  const int wave = tid >> 6;
  const int lane = tid & 63;
  const int lcol = lane & 15;
  const int quad = lane >> 4;
  const int rA = wave * 16 + lcol;
  bf16x8 ah0 = *(const bf16x8*)&sxh[rA * XST + 0  + quad * 8];
  bf16x8 ah1 = *(const bf16x8*)&sxh[rA * XST + 32 + quad * 8];
  bf16x8 al0 = *(const bf16x8*)&sxl[rA * XST + 0  + quad * 8];
  bf16x8 al1 = *(const bf16x8*)&sxl[rA * XST + 32 + quad * 8];
  __syncthreads();

  float bd[4], b2[4];
  int   bi[4];
#pragma unroll
  for (int i = 0; i < 4; ++i) { bd[i] = 3.0e38f; b2[i] = 3.0e38f; bi[i] = 0; }

  const char* kfg = kfrag;

#define VQM_ISSUE(C, B)                                                      \
  if ((C) < 128) {                                                           \
    const char* s = kfg + (size_t)(C) * 4096 + (lane << 4);                  \
    char* d = kbuf + (B) * 4096;                                             \
    GLOAD_LDS(s, d);                                                         \
    GLOAD_LDS(s + 1024, d + 1024);                                           \
    GLOAD_LDS(s + 2048, d + 2048);                                           \
    GLOAD_LDS(s + 3072, d + 3072);                                           \
  }

  {
    const float4* k24 = (const float4*)k2g;
    *(float4*)&k2f[tid * 8]     = k24[tid * 2];
    *(float4*)&k2f[tid * 8 + 4] = k24[tid * 2 + 1];
  }
  if (wave == 0) {
    VQM_ISSUE(0, 0)
    VQM_ISSUE(1, 1)
  }
  asm volatile("s_waitcnt lgkmcnt(0)\n\ts_barrier" ::: "memory");

#define VQM_STEP(C, RB, PB, WAITIMM)                                         \
  {                                                                          \
    if (wave == 0) __builtin_amdgcn_s_waitcnt(WAITIMM);                      \
    SBAR();                                                                  \
    const char* tb = kbuf + (RB) * 4096;                                     \
    bf16x8 bh0 = *(const bf16x8*)(tb + 0    + (lane << 4));                  \
    bf16x8 bh1 = *(const bf16x8*)(tb + 1024 + (lane << 4));                  \
    bf16x8 bl0 = *(const bf16x8*)(tb + 2048 + (lane << 4));                  \
    bf16x8 bl1 = *(const bf16x8*)(tb + 3072 + (lane << 4));                  \
    float k2c = k2f[(C) * 16 + lcol];                                        \
    if (wave == 0) { VQM_ISSUE((C) + 2, PB) }                                \
    f32x4 p = {0.f, 0.f, 0.f, 0.f};                                          \
    p = __builtin_amdgcn_mfma_f32_16x16x32_bf16(ah0, bh0, p, 0, 0, 0);       \
    p = __builtin_amdgcn_mfma_f32_16x16x32_bf16(ah1, bh1, p, 0, 0, 0);       \
    p = __builtin_amdgcn_mfma_f32_16x16x32_bf16(ah0, bl0, p, 0, 0, 0);       \
    p = __builtin_amdgcn_mfma_f32_16x16x32_bf16(ah1, bl1, p, 0, 0, 0);       \
    p = __builtin_amdgcn_mfma_f32_16x16x32_bf16(al0, bh0, p, 0, 0, 0);       \
    p = __builtin_amdgcn_mfma_f32_16x16x32_bf16(al1, bh1, p, 0, 0, 0);       \
    const int code = (C) * 16 + lcol;                                        \
    _Pragma("unroll")                                                        \
    for (int i = 0; i < 4; ++i) {                                            \
      float d0 = fmaf(-2.f, p[i], k2c);                                      \
      float nb2 = __builtin_amdgcn_fmed3f(bd[i], d0, b2[i]);                 \
      bool lt0 = d0 < bd[i];                                                 \
      bd[i] = lt0 ? d0 : bd[i];                                              \
      bi[i] = lt0 ? code : bi[i];                                            \
      b2[i] = nb2;                                                           \
    }                                                                        \
  }

  for (int c = 0; c < 126; c += 3) {
    VQM_STEP(c,     0, 2, WAIT_VM4)
    VQM_STEP(c + 1, 1, 0, WAIT_VM4)
    VQM_STEP(c + 2, 2, 1, WAIT_VM4)
  }
  VQM_STEP(126, 0, 2, WAIT_VM4)
  VQM_STEP(127, 1, 0, WAIT_VM0)
#undef VQM_STEP
#undef VQM_ISSUE

#pragma unroll
  for (int m = 1; m < 16; m <<= 1) {
#pragma unroll
    for (int i = 0; i < 4; ++i) {
      float od  = __shfl_xor(bd[i], m, 64);
      float od2 = __shfl_xor(b2[i], m, 64);
      int   oi  = __shfl_xor(bi[i], m, 64);
      float nb2 = fminf(fminf(b2[i], od2), fmaxf(bd[i], od));
      bool take = (od < bd[i]) || (od == bd[i] && oi < bi[i]);
      bd[i] = take ? od : bd[i];
      bi[i] = take ? oi : bi[i];
      b2[i] = nb2;
    }
  }

  __syncthreads();
  if (tid == 0) *sFlagCnt = 0;
  __syncthreads();

  float fit_p = 0.f;
  if (lcol == 0) {
#pragma unroll
    for (int i = 0; i < 4; ++i) {
      int rloc = wave * 16 + quad * 4 + i;
      int rowg = row0 + rloc;
      out[XL_OFF + rowg] = (float)bi[i];
      sIdx[rloc] = bi[i];
      fit_p += bd[i];
      if (b2[i] - bd[i] < TAU) {
        int slot = atomicAdd(sFlagCnt, 1);
        sFlagList[slot] = rowg;
      }
    }
  }
  __syncthreads();

  int nloc = *sFlagCnt;
  if (tid == 0 && nloc > 0) *sFlagBase = atomicAdd(flag_cnt, nloc);
  __syncthreads();
  if (tid < nloc) {
    int gs = *sFlagBase + tid;
    if (gs < MAXFLAG) flags[gs] = sFlagList[tid];
  }

  {
    int rr = tid >> 2, q4 = tid & 3;
    const float4* kr4 = (const float4*)(kg + (size_t)sIdx[rr] * WDIM) + q4 * 4;
    float4* dst = (float4*)&kd[rr * 68 + q4 * 16];
#pragma unroll
    for (int j = 0; j < 4; ++j) dst[j] = kr4[j];
  }
  __syncthreads();

  float commit_p = 0.f;
  float* xdb = out + XD_OFF + (size_t)n * WDIM * TDIM + t0 + r;
#pragma unroll 8
  for (int i = 0; i < 16; ++i) {
    int w = 4 * i + wh;
    float xvv = xb[(size_t)w * TDIM];
    float kvv = kd[r * 68 + w];
    float df = kvv - xvv;
    commit_p = fmaf(df, df, commit_p);
    xdb[(size_t)w * TDIM] = kvv;
  }

  float v0 = sxp, v1 = x2p, v2 = commit_p, v3 = fit_p;
#pragma unroll
  for (int off = 32; off > 0; off >>= 1) {
    v0 += __shfl_down(v0, off, 64);
    v1 += __shfl_down(v1, off, 64);
    v2 += __shfl_down(v2, off, 64);
    v3 += __shfl_down(v3, off, 64);
  }
  if (lane == 0) {
    sPair[wave * 4 + 0] = v0;
    sPair[wave * 4 + 1] = v1;
    sPair[wave * 4 + 2] = v2;
    sPair[wave * 4 + 3] = v3;
  }
  __syncthreads();
  if (tid == 0) {
    float x2sum = sPair[1] + sPair[5] + sPair[9] + sPair[13];
    part[0 * NBLK + blk] = sPair[0] + sPair[4] + sPair[8] + sPair[12];
    part[1 * NBLK + blk] = x2sum;
    part[2 * NBLK + blk] = sPair[2] + sPair[6] + sPair[10] + sPair[14];
    part[3 * NBLK + blk] = (sPair[3] + sPair[7] + sPair[11] + sPair[15]) + x2sum;
  }
}

// recheck pass 1 (R2/R3-proven form): persistent grid; item = (flagged row,
// 256-code segment). kT coalesced; identical fmaf chain -> bit-identical
// distances. Lean registers (no outer unroll) -> no scratch.
__launch_bounds__(256, 4)
__global__ void recheck_scan(const float* __restrict__ x,
                             const float* __restrict__ kg,
                             const float* __restrict__ kT,
                             const float* __restrict__ k2g,
                             const int* __restrict__ flag_cnt,
                             const int* __restrict__ flags,
                             u64* __restrict__ slots) {
  __shared__ float sx[WDIM];
  __shared__ float sx2s;
  const int tid = threadIdx.x;
  int nf = *flag_cnt;
  if (nf > MAXFLAG) nf = MAXFLAG;
  const int total = nf * 8;

  for (int g = blockIdx.x; g < total; g += 2048) {
    const int fi  = g >> 3;
    const int seg = g & 7;
    const int row = flags[fi];
    const int n = row >> 13;
    const int t = row & (TDIM - 1);
    if (tid < WDIM) sx[tid] = x[(size_t)n * WDIM * TDIM + (size_t)tid * TDIM + t];
    __syncthreads();
    if (tid == 0) {   // np-pairwise x2
      float r8[8];
#pragma unroll
      for (int l = 0; l < 8; ++l) r8[l] = __fmul_rn(sx[l], sx[l]);
      for (int i = 8; i < WDIM; i += 8) {
#pragma unroll
        for (int l = 0; l < 8; ++l)
          r8[l] = __fadd_rn(r8[l], __fmul_rn(sx[i + l], sx[i + l]));
      }
      sx2s = __fadd_rn(__fadd_rn(__fadd_rn(r8[0], r8[1]), __fadd_rn(r8[2], r8[3])),
                       __fadd_rn(__fadd_rn(r8[4], r8[5]), __fadd_rn(r8[6], r8[7])));
    }
    __syncthreads();

    const int j = seg * 256 + tid;
    float c = 0.f;
    if (kT) {
#pragma unroll
      for (int w = 0; w < WDIM; ++w)
        c = __fmaf_rn(sx[w], kT[(size_t)w * KBINS + j], c);
    } else {
      const float* kr = kg + (size_t)j * WDIM;
#pragma unroll
      for (int w = 0; w < WDIM; ++w)
        c = __fmaf_rn(sx[w], kr[w], c);
    }
    float d = __fadd_rn(__fsub_rn(sx2s, __fmul_rn(2.0f, c)), k2g[j]);

    u64 key = ((u64)__float_as_uint(d) << 32) | (unsigned)j;
#pragma unroll
    for (int off = 32; off > 0; off >>= 1) {
      u64 o = __shfl_down((unsigned long long)key, off, 64);
      if (o < key) key = o;
    }
    if ((tid & 63) == 0) atomicMin(&slots[fi], key);
    __syncthreads();
  }
}

// recheck pass 2: persistent write-back.
__global__ void recheck_write(const float* __restrict__ kg,
                              const int* __restrict__ flag_cnt,
                              const int* __restrict__ flags,
                              const u64* __restrict__ slots,
                              float* __restrict__ out) {
  int nf = *flag_cnt;
  if (nf > MAXFLAG) nf = MAXFLAG;
  const int w = threadIdx.x;
  for (int fi = blockIdx.x; fi < nf; fi += 256) {
    const int row = flags[fi];
    const int n = row >> 13;
    const int t = row & (TDIM - 1);
    const int j = (int)(slots[fi] & 0xFFFFFFFFULL);
    if (w == 0) out[XL_OFF + row] = (float)j;
    out[XD_OFF + (size_t)n * WDIM * TDIM + (size_t)w * TDIM + t] = kg[(size_t)j * WDIM + w];
  }
}

// finalize: sum per-block partials (fp64) + emit the 3 scalars.
__global__ void finalize_kernel(const float* __restrict__ part, float* __restrict__ out) {
  __shared__ double sred[4][64];
  const int tid = threadIdx.x;     // 256
  const int lane = tid & 63;
  const int wv = tid >> 6;
  double a[4] = {0.0, 0.0, 0.0, 0.0};
  for (int i = tid; i < NBLK; i += 256) {
#pragma unroll
    for (int q = 0; q < 4; ++q) a[q] += (double)part[q * NBLK + i];
  }
#pragma unroll
  for (int off = 32; off > 0; off >>= 1) {
#pragma unroll
    for (int q = 0; q < 4; ++q)
      a[q] += __shfl_down(a[q], off, 64);
  }
  if (lane == 0) {
#pragma unroll
    for (int q = 0; q < 4; ++q) sred[q][wv] = a[q];
  }
  __syncthreads();
  if (tid == 0) {
    double s0 = 0, s1 = 0, s2 = 0, s3 = 0;
#pragma unroll
    for (int wv2 = 0; wv2 < 4; ++wv2) {
      s0 += sred[0][wv2]; s1 += sred[1][wv2];
      s2 += sred[2][wv2]; s3 += sred[3][wv2];
    }
    double size = (double)XSIZE;
    double commit = s2 / size;
    double fit = s3 / (double)NROWS;
    double mean = s0 / size;
    double var = s1 / size - mean * mean;
    if (var < 0.0) var = 0.0;
    out[SCAL_OFF + 0] = (float)commit;
    out[SCAL_OFF + 1] = (float)fit;
    out[SCAL_OFF + 2] = (float)sqrt(var);
  }
}

extern "C" void kernel_launch(void* const* d_in, const int* in_sizes, int n_in,
                              void* d_out, int out_size, void* d_ws, size_t ws_size,
                              hipStream_t stream) {
  const float* x = (const float*)d_in[0];
  const float* kg = (const float*)d_in[1];
  float* out = (float*)d_out;
  float* k2   = (float*)((char*)d_ws + WS_K2_OFF);
  int* cnt    = (int*)((char*)d_ws + WS_CNT_OFF);
  int* flags  = (int*)((char*)d_ws + WS_FLAG_OFF);
  u64* slots  = (u64*)((char*)d_ws + WS_SLOT_OFF);
  float* part = (float*)((char*)d_ws + WS_PART_OFF);
  char* kfrag = (char*)d_ws + WS_KF_OFF;
  float* kT   = (ws_size >= WS_KT_END) ? (float*)((char*)d_ws + WS_KT_OFF) : nullptr;
  u64* res    = (ws_size >= WS_RES_END) ? (u64*)((char*)d_ws + WS_RES_OFF) : nullptr;

  hipLaunchKernelGGL(prep_kernel, dim3(KBINS / 16), dim3(256), 0, stream,
                     kg, k2, kfrag, kT, cnt, slots);
  if (res) {
    hipLaunchKernelGGL(vq_scan, dim3(2 * NBLK), dim3(256), 0, stream,
                       x, k2, kfrag, res);
    hipLaunchKernelGGL(vq_emit, dim3(NBLK), dim3(256), 0, stream,
                       x, kg, res, out, part, cnt, flags);
  } else {
    hipLaunchKernelGGL(vq_mono, dim3(NBLK), dim3(256), 0, stream,
                       x, kg, k2, kfrag, out, part, cnt, flags);
  }
  hipLaunchKernelGGL(recheck_scan, dim3(2048), dim3(256), 0, stream,
                     x, kg, kT, k2, cnt, flags, slots);
  hipLaunchKernelGGL(recheck_write, dim3(256), dim3(WDIM), 0, stream,
                     kg, cnt, flags, slots, out);
  hipLaunchKernelGGL(finalize_kernel, dim3(1), dim3(256), 0, stream, part, out);
}